// Round 8
// baseline (7322.324 us; speedup 1.0000x reference)
//
#include <hip/hip_runtime.h>
#include <hip/hip_bf16.h>
#include <math.h>

// Problem constants: T=512, B=4, H=8, D=64, BH=32, C2=128 (=2*D), d_model=512.
#define M1 (1<<20)
// ws arena (float slot offsets). Timeline: [proj/graph/ccor phase] then [conv loop] then [out gemm].
#define OFF_QT   (0)            // qT [32][64][512] fp32 (whole session)
#define OFF_KT   (1*M1)         // kT [32][64][512] fp32 (whole session)
#define OFF_XT   (2*M1)         // xpadT [32][768][128] bf16 (1.5 M1 slots) — v2 padded, t-major
#define OFF_QS   (4*M1)         // qS (dead after ccor) — reused as SP0 in conv loop
#define OFF_PART (5*M1)         // ccor partials (dead after redmc) — part of SP0
#define OFF_SP0  (4*M1)         // split-K partial 0 [32*512*128] fp32 (conv loop)
#define OFF_AGGA (6*M1)         // aggA [2048][1024] fp32 (accumulated by conv2/resid)
#define OFF_H    (8*M1)         // hpadT [32][768][128] bf16 (1.5 M1 slots, conv loop)
#define OFF_W1   (10*M1)        // conv1 W bf16 (hi-only), swizzled: exactly 2M floats at ks=256
#define OFF_SP1  (12*M1)        // split-K partial 1
#define OFF_W2   (14*M1)        // conv2 W
#define OFF_SP2  (16*M1)        // split-K partial 2
#define OFF_TAIL (18*M1)
#define OFF_B1   (OFF_TAIL)
#define OFF_B2   (OFF_TAIL+128)
#define OFF_MC   (OFF_TAIL+256)        // mean_corr[512]
#define OFF_S    (OFF_TAIL+1024)       // S [64][64]
#define OFF_DIMA (OFF_TAIL+1024+4096)  // dim_cor accum [64][64]
#define OFF_META (OFF_TAIL+1024+8192)  // u32: idx6[6], ks6[6], pad, keys@24 (48 u32)
#define OFF_TMPC (OFF_META+128)        // floats: tmp_corr[6]

typedef __attribute__((ext_vector_type(8))) short bfrag;   // 8 bf16 = 4 VGPRs
typedef __attribute__((ext_vector_type(4))) float ffrag;   // MFMA C/D

__device__ __forceinline__ unsigned short f2bf(float f) {
  __hip_bfloat16 h = __float2bfloat16(f);   // RNE
  return *reinterpret_cast<unsigned short*>(&h);
}
__device__ __forceinline__ float bf2f(unsigned short u) {
  return __uint_as_float(((unsigned)u) << 16);
}

// ---------------- Threefry-2x32 core ----------------
__device__ __forceinline__ void tf_block(unsigned k0, unsigned k1, unsigned x0, unsigned x1,
                                         unsigned& o0, unsigned& o1) {
  unsigned k2 = k0 ^ k1 ^ 0x1BD11BDAu;
  x0 += k0; x1 += k1;
#define TFR(r) { x0 += x1; x1 = (x1<<(r))|(x1>>(32-(r))); x1 ^= x0; }
  TFR(13) TFR(15) TFR(26) TFR(6)   x0 += k1; x1 += k2 + 1u;
  TFR(17) TFR(29) TFR(16) TFR(24)  x0 += k2; x1 += k0 + 2u;
  TFR(13) TFR(15) TFR(26) TFR(6)   x0 += k0; x1 += k1 + 3u;
  TFR(17) TFR(29) TFR(16) TFR(24)  x0 += k1; x1 += k2 + 4u;
  TFR(13) TFR(15) TFR(26) TFR(6)   x0 += k2; x1 += k0 + 5u;
#undef TFR
  o0 = x0; o1 = x1;
}

// jax_threefry_partitionable (default since 0.4.36): counter (0, e), result = out0^out1.
__device__ __forceinline__ unsigned tf_bits32(unsigned k0, unsigned k1, unsigned e) {
  unsigned o0, o1;
  tf_block(k0, k1, 0u, e, o0, o1);
  return o0 ^ o1;
}

// Giles/XLA erfinv (f32)
__device__ __forceinline__ float erfinv32(float x) {
  float w = -log1pf(-x*x);
  float p;
  if (w < 5.0f) {
    w = w - 2.5f;
    p = 2.81022636e-08f;
    p = fmaf(p, w, 3.43273939e-07f);
    p = fmaf(p, w, -3.5233877e-06f);
    p = fmaf(p, w, -4.39150654e-06f);
    p = fmaf(p, w, 0.00021858087f);
    p = fmaf(p, w, -0.00125372503f);
    p = fmaf(p, w, -0.00417768164f);
    p = fmaf(p, w, 0.246640727f);
    p = fmaf(p, w, 1.50140941f);
  } else {
    w = sqrtf(w) - 3.0f;
    p = -0.000200214257f;
    p = fmaf(p, w, 0.000100950558f);
    p = fmaf(p, w, 0.00134934322f);
    p = fmaf(p, w, -0.00367342844f);
    p = fmaf(p, w, 0.00573950773f);
    p = fmaf(p, w, -0.0076224613f);
    p = fmaf(p, w, 0.00943887047f);
    p = fmaf(p, w, 1.00167406f);
    p = fmaf(p, w, 2.83297682f);
  }
  return p * x;
}

__device__ __forceinline__ float bits_to_normal(unsigned b) {
  float f = __uint_as_float((b >> 9) | 0x3F800000u) - 1.0f;
  const float lo = -0.99999994f;
  float u = fmaxf(lo, f * 2.0f + lo);
  return 1.4142135623730951f * erfinv32(u);
}

// ---------------- fp32 GEMM: C[2048xN=512] = A[2048xK] @ B[512xK]^T + bias ----------------
// MODE 0: row-major fp32 out. MODE 1: scatter fp32 to qT/kT [bh][d][t]. MODE 2: scatter bf16 to xpadT.
template<int MODE>
__global__ __launch_bounds__(256) void gemm_k(const float* __restrict__ A, const float* __restrict__ B,
                                              const float* __restrict__ bias, float* __restrict__ Cout,
                                              int K) {
  __shared__ float As[16][65];
  __shared__ float Bs[16][65];
  int tid = threadIdx.x;
  int tx = tid & 15, ty = tid >> 4;
  int rBase = blockIdx.x * 64;
  int cBase = blockIdx.y * 64;
  float acc[4][4] = {};
  int m = tid & 63, kq = tid >> 6;
  for (int kk = 0; kk < K; kk += 16) {
    float4 av = *(const float4*)(A + (size_t)(rBase + m) * K + kk + kq * 4);
    float4 bv = *(const float4*)(B + (size_t)(cBase + m) * K + kk + kq * 4);
    As[kq*4+0][m] = av.x; As[kq*4+1][m] = av.y; As[kq*4+2][m] = av.z; As[kq*4+3][m] = av.w;
    Bs[kq*4+0][m] = bv.x; Bs[kq*4+1][m] = bv.y; Bs[kq*4+2][m] = bv.z; Bs[kq*4+3][m] = bv.w;
    __syncthreads();
#pragma unroll
    for (int k = 0; k < 16; ++k) {
      float a[4], b[4];
#pragma unroll
      for (int i = 0; i < 4; ++i) a[i] = As[k][ty + 16*i];
#pragma unroll
      for (int j = 0; j < 4; ++j) b[j] = Bs[k][tx + 16*j];
#pragma unroll
      for (int i = 0; i < 4; ++i)
#pragma unroll
        for (int j = 0; j < 4; ++j) acc[i][j] += a[i] * b[j];
    }
    __syncthreads();
  }
#pragma unroll
  for (int i = 0; i < 4; ++i) {
    int r = rBase + ty + 16*i;
    int t = r >> 2, bb = r & 3;
#pragma unroll
    for (int j = 0; j < 4; ++j) {
      int c = cBase + tx + 16*j;
      float v = acc[i][j] + bias[c];
      if (MODE == 0) {
        Cout[(size_t)r * 512 + c] = v;
      } else if (MODE == 1) {
        int h = c >> 6, d = c & 63;
        Cout[((size_t)(bb*8 + h) * 64 + d) * 512 + t] = v;
      } else {
        int h = c >> 6, d = c & 63;
        ((unsigned short*)Cout)[((size_t)((bb*8 + h) * 768) + 256 + t) * 128 + d] = f2bf(v);
      }
    }
  }
}

// fill xpadT channels 64..127: xpadT[bh][256+t][64+dd] = bf16(w[dd][bh])
__global__ void fillw_k(const float* __restrict__ warr, unsigned short* __restrict__ xpad) {
  int e = blockIdx.x * 256 + threadIdx.x;   // < 32*512*64 = 2^20
  int dd = e & 63, t = (e >> 6) & 511, bh = e >> 15;
  xpad[((size_t)(bh * 768) + 256 + t) * 128 + 64 + dd] = f2bf(warr[dd * 32 + bh]);
}

// cos-sim graph: ji_mat (output), top-32 per row, tk_w softmax, S scatter matrix
__global__ __launch_bounds__(256) void graph_k(const float* __restrict__ warr,
                                               float* __restrict__ Sout, float* __restrict__ jiout) {
  __shared__ float wl[64][32];
  __shared__ float cosl[64][65];
  __shared__ float scratch[64][64];
  __shared__ float nrm[64];
  __shared__ float tkv[64][32];
  __shared__ int   tki[64][32];
  int tid = threadIdx.x;
  for (int e = tid; e < 64*32; e += 256) wl[e >> 5][e & 31] = warr[e];
  __syncthreads();
  {
    int i = tid >> 2;
    for (int jj = 0; jj < 16; ++jj) {
      int j = (tid & 3) * 16 + jj;
      float s = 0;
      for (int n = 0; n < 32; ++n) s += wl[i][n] * wl[j][n];
      cosl[i][j] = s;
    }
  }
  __syncthreads();
  if (tid < 64) nrm[tid] = sqrtf(cosl[tid][tid]);
  __syncthreads();
  {
    int i = tid >> 2;
    for (int jj = 0; jj < 16; ++jj) {
      int j = (tid & 3) * 16 + jj;
      float v = cosl[i][j] / (nrm[i] * nrm[j]);
      cosl[i][j] = v;
      scratch[i][j] = v;
    }
  }
  __syncthreads();
  if (tid < 64) {
    int i = tid;
    float mx = -1e30f;
    for (int j = 0; j < 64; ++j) mx = fmaxf(mx, cosl[i][j]);
    float sum = 0;
    for (int j = 0; j < 64; ++j) sum += expf(cosl[i][j] - mx);
    float inv = 1.0f / sum;
    for (int j = 0; j < 64; ++j) jiout[i * 64 + j] = expf(cosl[i][j] - mx) * inv;
    for (int m = 0; m < 32; ++m) {
      float best = -1e30f; int bi = 0;
      for (int j = 0; j < 64; ++j) { float v = scratch[i][j]; if (v > best) { best = v; bi = j; } }
      tkv[i][m] = best; tki[i][m] = bi; scratch[i][bi] = -1e30f;
    }
    float m0 = tkv[i][0], s2 = 0;
    for (int m = 0; m < 32; ++m) s2 += expf(tkv[i][m] - m0);
    float i2 = 1.0f / s2;
    for (int m = 0; m < 32; ++m) tkv[i][m] = expf(tkv[i][m] - m0) * i2;
  }
  __syncthreads();
  for (int e = tid; e < 4096; e += 256) scratch[e >> 6][e & 63] = 0.0f;
  __syncthreads();
  if (tid < 64) for (int m = 0; m < 32; ++m) scratch[tid][tki[tid][m]] = tkv[tid][m];
  __syncthreads();
  for (int e = tid; e < 4096; e += 256) Sout[e] = scratch[e >> 6][e & 63];
}

// qS[bh][j][s] = sum_i S[i][j] * qT[bh][i][s]
__global__ __launch_bounds__(256) void qs_k(const float* __restrict__ qT, const float* __restrict__ S,
                                            float* __restrict__ qS) {
  __shared__ float Sl[64][64];
  int tid = threadIdx.x;
  for (int e = tid; e < 4096; e += 256) Sl[e >> 6][e & 63] = S[e];
  __syncthreads();
  int bh = blockIdx.x;
  int s = blockIdx.y * 64 + (tid & 63);
  int jg = (tid >> 6) * 16;
  float acc[16] = {};
  const float* qb = qT + (size_t)bh * 64 * 512 + s;
  for (int i = 0; i < 64; ++i) {
    float qv = qb[i * 512];
#pragma unroll
    for (int jj = 0; jj < 16; ++jj) acc[jj] += Sl[i][jg + jj] * qv;
  }
  float* ob = qS + (size_t)bh * 64 * 512 + s;
#pragma unroll
  for (int jj = 0; jj < 16; ++jj) ob[(jg + jj) * 512] = acc[jj];
}

// per (bh,j) circular cross-correlation partials
__global__ __launch_bounds__(256) void ccor_k(const float* __restrict__ qS, const float* __restrict__ kT,
                                              float* __restrict__ part) {
  __shared__ float qr[512], kr[512];
  int tid = threadIdx.x;
  int bj = blockIdx.x;
  const float* q = qS + (size_t)bj * 512;
  const float* k = kT + (size_t)bj * 512;
  qr[tid] = q[tid]; qr[tid + 256] = q[tid + 256];
  kr[tid] = k[tid]; kr[tid + 256] = k[tid + 256];
  __syncthreads();
  int t0 = tid, t1 = tid + 256;
  float a0 = 0, a1 = 0;
  for (int s = 0; s < 512; ++s) {
    float qv = qr[s];
    a0 += qv * kr[(s - t0) & 511];
    a1 += qv * kr[(s - t1) & 511];
  }
  part[(size_t)bj * 512 + t0] = a0;
  part[(size_t)bj * 512 + t1] = a1;
}

__global__ void redmc_k(const float* __restrict__ part, float* __restrict__ mc) {
  int t = blockIdx.x * 256 + threadIdx.x;
  float s = 0;
  for (int p = 0; p < 2048; ++p) s += part[(size_t)p * 512 + t];
  mc[t] = s * (1.0f / 2048.0f);
}

// top-6 + softmax + ks fold + threefry key schedule
__global__ void top6_k(const float* __restrict__ mc, unsigned* metaU, float* tmpc) {
  if (threadIdx.x != 0 || blockIdx.x != 0) return;
  float vals[6]; int idx[6];
  for (int m = 0; m < 6; ++m) {
    float best = -1e30f; int bi = 0;
    for (int t = 0; t < 512; ++t) {
      bool skip = false;
      for (int p = 0; p < m; ++p) if (idx[p] == t) skip = true;
      if (skip) continue;
      float v = mc[t];
      if (v > best) { best = v; bi = t; }
    }
    vals[m] = best; idx[m] = bi;
  }
  float mx = vals[0], s = 0;
  for (int m = 0; m < 6; ++m) s += expf(vals[m] - mx);
  for (int m = 0; m < 6; ++m) tmpc[m] = expf(vals[m] - mx) / s;
  for (int m = 0; m < 6; ++m) {
    metaU[m] = (unsigned)idx[m];
    int ind = idx[m];
    if (ind >= 256) ind = 512 - ind;
    metaU[6 + m] = (unsigned)ind;
    unsigned kk0, kk1; tf_block(0u, 1u, 0u, (unsigned)ind, kk0, kk1);
    unsigned* kp = metaU + 24 + m * 8;
#pragma unroll
    for (int i = 0; i < 4; ++i) {
      unsigned o0, o1;
      tf_block(kk0, kk1, 0u, (unsigned)i, o0, o1);
      kp[2*i]   = o0;
      kp[2*i+1] = o1;
    }
    // key0 -> w1 (normal), key1 -> b1 (uniform), key2 -> w2 (normal), key3 -> b2 (uniform)
  }
}

// conv weights, hi-only bf16, stored PRE-SWIZZLED for conflict-free LDS use:
// short index d = kp*16384 + co*128 + slot*8 + j, where slot = chunk ^ (co&15),
// chunk = ci>>3, j = ci&7. jax source linear index e over (co,ci,kp).
// grid (2048, 2): each thread generates 8 weights. grid.y: 0 -> w1 (key0), 1 -> w2 (key2).
__global__ __launch_bounds__(256) void genw_k(float* __restrict__ ws, const unsigned* __restrict__ metaU,
                                              int sel) {
  int ks = (int)metaU[6 + sel];
  if (ks <= 1) return;
  int n = ks << 14;
  const unsigned* kp_ = metaU + 24 + sel * 8 + (blockIdx.y ? 4 : 0);
  unsigned k0 = kp_[0], k1 = kp_[1];
  unsigned short* dst = (unsigned short*)(ws + (blockIdx.y ? OFF_W2 : OFF_W1));
  int base = blockIdx.x * 256 + threadIdx.x;
#pragma unroll
  for (int jj = 0; jj < 8; ++jj) {
    int d = base + jj * 524288;
    if (d < n) {
      int kp = d >> 14, rem = d & 16383;
      int co = rem >> 7, slot = (rem >> 3) & 15, j = d & 7;
      int ci = ((slot ^ (co & 15)) << 3) + j;
      unsigned e = (unsigned)((co * 128 + ci) * ks + kp);
      float w = 0.01f * bits_to_normal(tf_bits32(k0, k1, e));
      dst[d] = f2bf(w);
    }
  }
}

__global__ void genb_k(float* __restrict__ ws, const unsigned* __restrict__ metaU, int sel) {
  int ks = (int)metaU[6 + sel];
  if (ks <= 1) return;
  int tid = threadIdx.x;
  int which = tid >> 7;     // 0: b1 (key1), 1: b2 (key3)
  int e = tid & 127;
  const unsigned* kp = metaU + 24 + sel * 8 + (which ? 6 : 2);
  float bound = (float)(1.0 / sqrt((double)(128 * ks)));
  unsigned bits = tf_bits32(kp[0], kp[1], (unsigned)e);
  float f = __uint_as_float((bits >> 9) | 0x3F800000u) - 1.0f;
  float r = f * (2.0f * bound) + (-bound);
  r = fmaxf(-bound, r);
  float* dst = ws + (which ? OFF_B2 : OFF_B1);
  dst[e] = r;
}

// ---------------- MFMA implicit-GEMM causal conv, split-K over kp ----------------
// partial[bh][t][co] = sum_{kp in [z*ks/3,(z+1)*ks/3)} sum_ci W[kp][co][ci]*xpad[bh][257-ks+t+kp][ci]
// grid (32 bh, 8 tt, 3 z) = 768 blocks (3/CU -> 12 waves/CU latency hiding).
// Block = 64t x 128co, 4 waves of 64t x 32co (acc = 8 ffrags = 32 VGPR).
// Per kp one 32 KB slab (128co x 128ci bf16, XOR-swizzled 16B chunks) staged to LDS; reads use
// slot = (kst*4+quad) ^ mrow -> conflict-free (round-6 verified: SQ_LDS_BANK_CONFLICT = 0).
// Register-prefetch of kp+1 slab.
// Store epilogue: acc fragments -> LDS [t_local][co] transpose (reusing lds_w, exactly 32 KB)
// -> linear float4 stores (1 KB/wave/instr). Round-7 PMC showed the fragment-pattern scattered
// 4B stores amplify ~70x at HBM (WRITE_SIZE 1.79 GB vs 25 MB logical) — transpose fixes that.
__global__ __launch_bounds__(256) void conv_split(const unsigned short* __restrict__ src,
                                                  const unsigned short* __restrict__ wgl,
                                                  float* __restrict__ sp0,
                                                  float* __restrict__ sp1,
                                                  float* __restrict__ sp2,
                                                  const unsigned* __restrict__ metaU, int sel) {
  int ks = (int)metaU[6 + sel];
  if (ks <= 1) return;
  __shared__ unsigned short lds_w[128 * 128];   // 32 KB, pre-swizzled linear; reused by epilogue
  int bh = blockIdx.x, tt = blockIdx.y, z = blockIdx.z;
  float* SP = (z == 0) ? sp0 : (z == 1) ? sp1 : sp2;
  int k0 = (z * ks) / 3, k1 = ((z + 1) * ks) / 3;
  int tid = threadIdx.x;
  int lane = tid & 63, wv = tid >> 6;
  int mrow = lane & 15, quad = lane >> 4;
  int t0 = tt * 64;
  int nbase = wv * 32;                          // wave's co base (2 n-subtiles)

  ffrag zero = {0.f, 0.f, 0.f, 0.f};
  ffrag acc[4][2];
#pragma unroll
  for (int m = 0; m < 4; ++m)
#pragma unroll
    for (int n = 0; n < 2; ++n) acc[m][n] = zero;

  if (k0 < k1) {
    const float4* g4 = (const float4*)wgl;      // [kp][2048 float4]
    float4 pf[8];
    {
      const float4* gs = g4 + (size_t)k0 * 2048;
#pragma unroll
      for (int i = 0; i < 8; ++i) pf[i] = gs[i * 256 + tid];
    }
    const unsigned short* ap = src + ((size_t)(bh * 768 + 257 - ks + t0 + mrow)) * 128 + quad * 8;

    for (int kp = k0; kp < k1; ++kp) {
      __syncthreads();   // all waves done reading lds_w from previous iteration
#pragma unroll
      for (int i = 0; i < 8; ++i)
        *(float4*)((char*)lds_w + (i * 256 + tid) * 16) = pf[i];
      if (kp + 1 < k1) {
        const float4* gs = g4 + (size_t)(kp + 1) * 2048;
#pragma unroll
        for (int i = 0; i < 8; ++i) pf[i] = gs[i * 256 + tid];
      }
      __syncthreads();   // slab visible to all waves
      const unsigned short* ab = ap + (size_t)kp * 128;
#pragma unroll
      for (int kst = 0; kst < 4; ++kst) {
        bfrag b8[2];
#pragma unroll
        for (int n = 0; n < 2; ++n) {
          int co = nbase + n * 16 + mrow;
          int slot = (kst * 4 + quad) ^ mrow;
          b8[n] = *(const bfrag*)((char*)lds_w + co * 256 + slot * 16);
        }
#pragma unroll
        for (int m = 0; m < 4; ++m) {
          bfrag a = *(const bfrag*)(ab + (size_t)m * 2048 + kst * 32);
#pragma unroll
          for (int n = 0; n < 2; ++n)
            acc[m][n] = __builtin_amdgcn_mfma_f32_16x16x32_bf16(a, b8[n], acc[m][n], 0, 0, 0);
        }
      }
    }
  }

  // --- coalesced store epilogue: acc -> LDS [t_local][co] -> linear float4 global stores ---
  __syncthreads();                 // done with lds_w as weight slab
  float* lds_f = (float*)lds_w;    // 64 x 128 fp32 tile = 32 KB
#pragma unroll
  for (int m = 0; m < 4; ++m) {
#pragma unroll
    for (int n = 0; n < 2; ++n) {
      int cog = nbase + n * 16 + mrow;
#pragma unroll
      for (int r = 0; r < 4; ++r) {
        int tl = m * 16 + quad * 4 + r;
        lds_f[tl * 128 + cog] = acc[m][n][r];
      }
    }
  }
  __syncthreads();
  // tile is contiguous in SP: base = (bh*512 + t0)*128
  float4* spv = (float4*)(SP + ((size_t)(bh * 512) + t0) * 128);
  const float4* lf4 = (const float4*)lds_f;
#pragma unroll
  for (int k = 0; k < 8; ++k)
    spv[k * 256 + tid] = lf4[k * 256 + tid];
}

// epilogue 1: h = relu(SP0+SP1+SP2 + b1) -> hpadT bf16   (grid 2048, 4 elems/thread)
__global__ void epi1_k(const float* __restrict__ sp0, const float* __restrict__ sp1,
                       const float* __restrict__ sp2, const float* __restrict__ bias,
                       unsigned short* __restrict__ hpad,
                       const unsigned* __restrict__ metaU, int sel) {
  int ks = (int)metaU[6 + sel];
  if (ks <= 1) return;
  int base = blockIdx.x * 1024 + threadIdx.x;
#pragma unroll
  for (int j = 0; j < 4; ++j) {
    int e = base + j * 256;   // < 2^21
    int c = e & 127, t = (e >> 7) & 511, bh = e >> 16;
    float v = fmaxf(sp0[e] + sp1[e] + sp2[e] + bias[c], 0.0f);
    hpad[((size_t)(bh * 768) + 256 + t) * 128 + c] = f2bf(v);
  }
}

// epilogue 2: aggA += tc * relu(relu(SP0+SP1+SP2 + b2) + v2)
__global__ void epi2_k(const float* __restrict__ sp0, const float* __restrict__ sp1,
                       const float* __restrict__ sp2, const float* __restrict__ bias,
                       const unsigned short* __restrict__ v2pad, float* __restrict__ aggA,
                       const unsigned* __restrict__ metaU, const float* __restrict__ tmpc, int sel) {
  int ks = (int)metaU[6 + sel];
  if (ks <= 1) return;
  float tc = tmpc[sel];
  int base = blockIdx.x * 1024 + threadIdx.x;
#pragma unroll
  for (int j = 0; j < 4; ++j) {
    int e = base + j * 256;
    int c = e & 127, t = (e >> 7) & 511, bh = e >> 16;
    float v = fmaxf(sp0[e] + sp1[e] + sp2[e] + bias[c], 0.0f);
    float v2 = bf2f(v2pad[((size_t)(bh * 768) + 256 + t) * 128 + c]);
    float tb = fmaxf(v + v2, 0.0f);
    aggA[((size_t)(t * 4 + (bh >> 3))) * 1024 + (bh & 7) * 128 + c] += tc * tb;
  }
}

// ks<=1 path: aggA += tc * v2   (grid 2048, 4 elems/thread)
__global__ void resid_k(const unsigned short* __restrict__ xpad, float* __restrict__ aggA,
                        const unsigned* __restrict__ metaU, const float* __restrict__ tmpc, int sel) {
  int ks = (int)metaU[6 + sel];
  if (ks > 1) return;
  float tc = tmpc[sel];
  int base = blockIdx.x * 1024 + threadIdx.x;
#pragma unroll
  for (int j = 0; j < 4; ++j) {
    int e = base + j * 256;   // < 32*512*128 = 2^21
    int c = e & 127, t = (e >> 7) & 511, bh = e >> 16;
    float v2 = bf2f(xpad[((size_t)(bh * 768) + 256 + t) * 128 + c]);
    aggA[((size_t)(t * 4 + (bh >> 3))) * 1024 + (bh & 7) * 128 + c] += tc * v2;
  }
}

// dim_cor partial: for (bh,sel): P[i][j] = sum_s qT[i][s]*kT[j][(s-t*)&511]; atomic += tc/32 * P
__global__ __launch_bounds__(256) void dimcor_k(const float* __restrict__ qT, const float* __restrict__ kT,
                                                float* __restrict__ dima, const unsigned* __restrict__ metaU,
                                                const float* __restrict__ tmpc) {
  __shared__ float qs[64][33];
  __shared__ float ksh[64][33];
  int bh = blockIdx.x, sel = blockIdx.y;
  int tstar = (int)metaU[sel];
  float scale = tmpc[sel] * (1.0f / 32.0f);
  int tid = threadIdx.x;
  int tx = tid & 15, ty = tid >> 4;
  float acc[4][4] = {};
  const float* qb = qT + (size_t)bh * 64 * 512;
  const float* kb = kT + (size_t)bh * 64 * 512;
  int ss = tid & 31, rr = tid >> 5;
  for (int s0 = 0; s0 < 512; s0 += 32) {
#pragma unroll
    for (int l = 0; l < 8; ++l) {
      int row = rr + 8 * l;
      qs[row][ss]  = qb[row * 512 + s0 + ss];
      ksh[row][ss] = kb[row * 512 + ((s0 + ss - tstar) & 511)];
    }
    __syncthreads();
#pragma unroll
    for (int s = 0; s < 32; ++s) {
      float a[4], b[4];
#pragma unroll
      for (int i = 0; i < 4; ++i) a[i] = qs[ty + 16*i][s];
#pragma unroll
      for (int j = 0; j < 4; ++j) b[j] = ksh[tx + 16*j][s];
#pragma unroll
      for (int i = 0; i < 4; ++i)
#pragma unroll
        for (int j = 0; j < 4; ++j) acc[i][j] += a[i] * b[j];
    }
    __syncthreads();
  }
#pragma unroll
  for (int i = 0; i < 4; ++i)
#pragma unroll
    for (int j = 0; j < 4; ++j)
      atomicAdd(&dima[(ty + 16*i) * 64 + tx + 16*j], acc[i][j] * scale);
}

__global__ void dsm_k(const float* __restrict__ dima, float* __restrict__ out) {
  int i = threadIdx.x;
  if (i >= 64) return;
  float mx = -1e30f;
  for (int j = 0; j < 64; ++j) mx = fmaxf(mx, 0.125f * dima[i * 64 + j]);
  float s = 0;
  for (int j = 0; j < 64; ++j) s += expf(0.125f * dima[i * 64 + j] - mx);
  float inv = 1.0f / s;
  for (int j = 0; j < 64; ++j) out[i * 64 + j] = expf(0.125f * dima[i * 64 + j] - mx) * inv;
}

extern "C" void kernel_launch(void* const* d_in, const int* in_sizes, int n_in,
                              void* d_out, int out_size, void* d_ws, size_t ws_size,
                              hipStream_t stream) {
  (void)in_sizes; (void)n_in; (void)out_size; (void)ws_size;
  const float* query  = (const float*)d_in[0];
  const float* key_in = (const float*)d_in[1];
  const float* value  = (const float*)d_in[2];
  const float* Wq = (const float*)d_in[4];
  const float* bq = (const float*)d_in[5];
  const float* Wk = (const float*)d_in[6];
  const float* bk = (const float*)d_in[7];
  const float* Wv = (const float*)d_in[8];
  const float* bv = (const float*)d_in[9];
  const float* Wo = (const float*)d_in[10];
  const float* bo = (const float*)d_in[11];
  const float* warr = (const float*)d_in[12];
  float* out = (float*)d_out;
  float* ws = (float*)d_ws;
  unsigned* metaU = (unsigned*)(ws + OFF_META);
  float* tmpc = ws + OFF_TMPC;
  unsigned short* xpad = (unsigned short*)(ws + OFF_XT);
  unsigned short* hpad = (unsigned short*)(ws + OFF_H);
  float* aggA = ws + OFF_AGGA;
  float* sp0 = ws + OFF_SP0;
  float* sp1 = ws + OFF_SP1;
  float* sp2 = ws + OFF_SP2;

  // zero: aggA (accumulated), xpad/hpad pad rows, dim_cor accum
  hipMemsetAsync(aggA, 0, (size_t)2048 * 1024 * 4, stream);
  hipMemsetAsync(xpad, 0, (size_t)32 * 768 * 128 * 2, stream);
  hipMemsetAsync(hpad, 0, (size_t)32 * 768 * 128 * 2, stream);
  hipMemsetAsync(ws + OFF_DIMA, 0, 4096 * sizeof(float), stream);

  // projections
  gemm_k<1><<<dim3(32, 8), 256, 0, stream>>>(query,  Wq, bq, ws + OFF_QT, 512);
  gemm_k<1><<<dim3(32, 8), 256, 0, stream>>>(key_in, Wk, bk, ws + OFF_KT, 512);
  gemm_k<2><<<dim3(32, 8), 256, 0, stream>>>(value,  Wv, bv, (float*)xpad, 512);
  fillw_k<<<4096, 256, 0, stream>>>(warr, xpad);

  // cos graph / ji_mat / S
  graph_k<<<1, 256, 0, stream>>>(warr, ws + OFF_S, out + 1048576 + 4096);

  // mean_corr via folded sparse-weighted circular correlation
  qs_k<<<dim3(32, 8), 256, 0, stream>>>(ws + OFF_QT, ws + OFF_S, ws + OFF_QS);
  ccor_k<<<2048, 256, 0, stream>>>(ws + OFF_QS, ws + OFF_KT, ws + OFF_PART);
  redmc_k<<<2, 256, 0, stream>>>(ws + OFF_PART, ws + OFF_MC);
  top6_k<<<1, 64, 0, stream>>>(ws + OFF_MC, metaU, tmpc);

  // temporal blocks (fixed worst-case grids; device-side ks gates the work)
  for (int sel = 0; sel < 6; ++sel) {
    genw_k<<<dim3(2048, 2), 256, 0, stream>>>(ws, metaU, sel);
    genb_k<<<1, 256, 0, stream>>>(ws, metaU, sel);
    conv_split<<<dim3(32, 8, 3), 256, 0, stream>>>(
        xpad, (unsigned short*)(ws + OFF_W1), sp0, sp1, sp2, metaU, sel);
    epi1_k<<<2048, 256, 0, stream>>>(sp0, sp1, sp2, ws + OFF_B1, hpad, metaU, sel);
    conv_split<<<dim3(32, 8, 3), 256, 0, stream>>>(
        hpad, (unsigned short*)(ws + OFF_W2), sp0, sp1, sp2, metaU, sel);
    epi2_k<<<2048, 256, 0, stream>>>(sp0, sp1, sp2, ws + OFF_B2, xpad, aggA, metaU, tmpc, sel);
    resid_k<<<2048, 256, 0, stream>>>(xpad, aggA, metaU, tmpc, sel);
  }

  // output projection (aggA is already [ (t*4+b) ][ h*128+c ])
  gemm_k<0><<<dim3(32, 8), 256, 0, stream>>>(aggA, Wo, bo, out, 1024);

  // dim_cor
  dimcor_k<<<dim3(32, 6), 256, 0, stream>>>(ws + OFF_QT, ws + OFF_KT, ws + OFF_DIMA, metaU, tmpc);
  dsm_k<<<1, 64, 0, stream>>>(ws + OFF_DIMA, out + 1048576);
}

// Round 9
// 5607.875 us; speedup vs baseline: 1.3057x; 1.3057x over previous
//
#include <hip/hip_runtime.h>
#include <hip/hip_bf16.h>
#include <math.h>

// Problem constants: T=512, B=4, H=8, D=64, BH=32, C2=128 (=2*D), d_model=512.
#define M1 (1<<20)
// ws arena (float slot offsets). Timeline: [proj/graph/ccor phase] then [conv loop] then [out gemm].
#define OFF_QT   (0)            // qT [32][64][512] fp32 (whole session)
#define OFF_KT   (1*M1)         // kT [32][64][512] fp32 (whole session)
#define OFF_XT   (2*M1)         // xpadT [32][768][128] bf16 (1.5 M1 slots) — v2 padded, t-major
#define OFF_QS   (4*M1)         // qS (dead after ccor) — reused as SP z0/z1 in conv loop
#define OFF_PART (5*M1)         // ccor partials (dead after redmc) — SP z1
#define OFF_AGGA (6*M1)         // aggA [2048][1024] fp32 (accumulated by epi2/resid)
#define OFF_H    (8*M1)         // hpadT [32][768][128] bf16 (1.5 M1 slots, conv loop)
#define OFF_W1   (10*M1)        // conv1 W bf16 (hi-only), swizzled: exactly 2M floats at ks=256
#define OFF_SPA  (12*M1)        // SP z2/z3 (bf16, 1M floats each)
#define OFF_W2   (14*M1)        // conv2 W
#define OFF_SPB  (16*M1)        // SP z4/z5
#define OFF_TAIL (18*M1)
#define OFF_B1   (OFF_TAIL)
#define OFF_B2   (OFF_TAIL+128)
#define OFF_MC   (OFF_TAIL+256)        // mean_corr[512]
#define OFF_S    (OFF_TAIL+1024)       // S [64][64]
#define OFF_DIMA (OFF_TAIL+1024+4096)  // dim_cor accum [64][64]
#define OFF_META (OFF_TAIL+1024+8192)  // u32: idx6[6], ks6[6], pad, keys@24 (48 u32)
#define OFF_TMPC (OFF_META+128)        // floats: tmp_corr[6]
// six bf16 split-K partial buffers, each 32*512*128 bf16 = 1M float slots:
// z0: 4M  z1: 5M  z2: 12M  z3: 13M  z4: 16M  z5: 17M

typedef __attribute__((ext_vector_type(8))) short bfrag;   // 8 bf16 = 4 VGPRs
typedef __attribute__((ext_vector_type(4))) float ffrag;   // MFMA C/D

__device__ __forceinline__ unsigned short f2bf(float f) {
  __hip_bfloat16 h = __float2bfloat16(f);   // RNE
  return *reinterpret_cast<unsigned short*>(&h);
}
__device__ __forceinline__ float bf2f(unsigned short u) {
  return __uint_as_float(((unsigned)u) << 16);
}

// ---------------- Threefry-2x32 core ----------------
__device__ __forceinline__ void tf_block(unsigned k0, unsigned k1, unsigned x0, unsigned x1,
                                         unsigned& o0, unsigned& o1) {
  unsigned k2 = k0 ^ k1 ^ 0x1BD11BDAu;
  x0 += k0; x1 += k1;
#define TFR(r) { x0 += x1; x1 = (x1<<(r))|(x1>>(32-(r))); x1 ^= x0; }
  TFR(13) TFR(15) TFR(26) TFR(6)   x0 += k1; x1 += k2 + 1u;
  TFR(17) TFR(29) TFR(16) TFR(24)  x0 += k2; x1 += k0 + 2u;
  TFR(13) TFR(15) TFR(26) TFR(6)   x0 += k0; x1 += k1 + 3u;
  TFR(17) TFR(29) TFR(16) TFR(24)  x0 += k1; x1 += k2 + 4u;
  TFR(13) TFR(15) TFR(26) TFR(6)   x0 += k2; x1 += k0 + 5u;
#undef TFR
  o0 = x0; o1 = x1;
}

// jax_threefry_partitionable (default since 0.4.36): counter (0, e), result = out0^out1.
__device__ __forceinline__ unsigned tf_bits32(unsigned k0, unsigned k1, unsigned e) {
  unsigned o0, o1;
  tf_block(k0, k1, 0u, e, o0, o1);
  return o0 ^ o1;
}

// Giles/XLA erfinv (f32)
__device__ __forceinline__ float erfinv32(float x) {
  float w = -log1pf(-x*x);
  float p;
  if (w < 5.0f) {
    w = w - 2.5f;
    p = 2.81022636e-08f;
    p = fmaf(p, w, 3.43273939e-07f);
    p = fmaf(p, w, -3.5233877e-06f);
    p = fmaf(p, w, -4.39150654e-06f);
    p = fmaf(p, w, 0.00021858087f);
    p = fmaf(p, w, -0.00125372503f);
    p = fmaf(p, w, -0.00417768164f);
    p = fmaf(p, w, 0.246640727f);
    p = fmaf(p, w, 1.50140941f);
  } else {
    w = sqrtf(w) - 3.0f;
    p = -0.000200214257f;
    p = fmaf(p, w, 0.000100950558f);
    p = fmaf(p, w, 0.00134934322f);
    p = fmaf(p, w, -0.00367342844f);
    p = fmaf(p, w, 0.00573950773f);
    p = fmaf(p, w, -0.0076224613f);
    p = fmaf(p, w, 0.00943887047f);
    p = fmaf(p, w, 1.00167406f);
    p = fmaf(p, w, 2.83297682f);
  }
  return p * x;
}

__device__ __forceinline__ float bits_to_normal(unsigned b) {
  float f = __uint_as_float((b >> 9) | 0x3F800000u) - 1.0f;
  const float lo = -0.99999994f;
  float u = fmaxf(lo, f * 2.0f + lo);
  return 1.4142135623730951f * erfinv32(u);
}

// ---------------- fp32 GEMM: C[2048xN=512] = A[2048xK] @ B[512xK]^T + bias ----------------
// MODE 0: row-major fp32 out. MODE 1: scatter fp32 to qT/kT [bh][d][t]. MODE 2: scatter bf16 to xpadT.
template<int MODE>
__global__ __launch_bounds__(256) void gemm_k(const float* __restrict__ A, const float* __restrict__ B,
                                              const float* __restrict__ bias, float* __restrict__ Cout,
                                              int K) {
  __shared__ float As[16][65];
  __shared__ float Bs[16][65];
  int tid = threadIdx.x;
  int tx = tid & 15, ty = tid >> 4;
  int rBase = blockIdx.x * 64;
  int cBase = blockIdx.y * 64;
  float acc[4][4] = {};
  int m = tid & 63, kq = tid >> 6;
  for (int kk = 0; kk < K; kk += 16) {
    float4 av = *(const float4*)(A + (size_t)(rBase + m) * K + kk + kq * 4);
    float4 bv = *(const float4*)(B + (size_t)(cBase + m) * K + kk + kq * 4);
    As[kq*4+0][m] = av.x; As[kq*4+1][m] = av.y; As[kq*4+2][m] = av.z; As[kq*4+3][m] = av.w;
    Bs[kq*4+0][m] = bv.x; Bs[kq*4+1][m] = bv.y; Bs[kq*4+2][m] = bv.z; Bs[kq*4+3][m] = bv.w;
    __syncthreads();
#pragma unroll
    for (int k = 0; k < 16; ++k) {
      float a[4], b[4];
#pragma unroll
      for (int i = 0; i < 4; ++i) a[i] = As[k][ty + 16*i];
#pragma unroll
      for (int j = 0; j < 4; ++j) b[j] = Bs[k][tx + 16*j];
#pragma unroll
      for (int i = 0; i < 4; ++i)
#pragma unroll
        for (int j = 0; j < 4; ++j) acc[i][j] += a[i] * b[j];
    }
    __syncthreads();
  }
#pragma unroll
  for (int i = 0; i < 4; ++i) {
    int r = rBase + ty + 16*i;
    int t = r >> 2, bb = r & 3;
#pragma unroll
    for (int j = 0; j < 4; ++j) {
      int c = cBase + tx + 16*j;
      float v = acc[i][j] + bias[c];
      if (MODE == 0) {
        Cout[(size_t)r * 512 + c] = v;
      } else if (MODE == 1) {
        int h = c >> 6, d = c & 63;
        Cout[((size_t)(bb*8 + h) * 64 + d) * 512 + t] = v;
      } else {
        int h = c >> 6, d = c & 63;
        ((unsigned short*)Cout)[((size_t)((bb*8 + h) * 768) + 256 + t) * 128 + d] = f2bf(v);
      }
    }
  }
}

// fill xpadT channels 64..127: xpadT[bh][256+t][64+dd] = bf16(w[dd][bh])
__global__ void fillw_k(const float* __restrict__ warr, unsigned short* __restrict__ xpad) {
  int e = blockIdx.x * 256 + threadIdx.x;   // < 32*512*64 = 2^20
  int dd = e & 63, t = (e >> 6) & 511, bh = e >> 15;
  xpad[((size_t)(bh * 768) + 256 + t) * 128 + 64 + dd] = f2bf(warr[dd * 32 + bh]);
}

// cos-sim graph: ji_mat (output), top-32 per row, tk_w softmax, S scatter matrix
__global__ __launch_bounds__(256) void graph_k(const float* __restrict__ warr,
                                               float* __restrict__ Sout, float* __restrict__ jiout) {
  __shared__ float wl[64][32];
  __shared__ float cosl[64][65];
  __shared__ float scratch[64][64];
  __shared__ float nrm[64];
  __shared__ float tkv[64][32];
  __shared__ int   tki[64][32];
  int tid = threadIdx.x;
  for (int e = tid; e < 64*32; e += 256) wl[e >> 5][e & 31] = warr[e];
  __syncthreads();
  {
    int i = tid >> 2;
    for (int jj = 0; jj < 16; ++jj) {
      int j = (tid & 3) * 16 + jj;
      float s = 0;
      for (int n = 0; n < 32; ++n) s += wl[i][n] * wl[j][n];
      cosl[i][j] = s;
    }
  }
  __syncthreads();
  if (tid < 64) nrm[tid] = sqrtf(cosl[tid][tid]);
  __syncthreads();
  {
    int i = tid >> 2;
    for (int jj = 0; jj < 16; ++jj) {
      int j = (tid & 3) * 16 + jj;
      float v = cosl[i][j] / (nrm[i] * nrm[j]);
      cosl[i][j] = v;
      scratch[i][j] = v;
    }
  }
  __syncthreads();
  if (tid < 64) {
    int i = tid;
    float mx = -1e30f;
    for (int j = 0; j < 64; ++j) mx = fmaxf(mx, cosl[i][j]);
    float sum = 0;
    for (int j = 0; j < 64; ++j) sum += expf(cosl[i][j] - mx);
    float inv = 1.0f / sum;
    for (int j = 0; j < 64; ++j) jiout[i * 64 + j] = expf(cosl[i][j] - mx) * inv;
    for (int m = 0; m < 32; ++m) {
      float best = -1e30f; int bi = 0;
      for (int j = 0; j < 64; ++j) { float v = scratch[i][j]; if (v > best) { best = v; bi = j; } }
      tkv[i][m] = best; tki[i][m] = bi; scratch[i][bi] = -1e30f;
    }
    float m0 = tkv[i][0], s2 = 0;
    for (int m = 0; m < 32; ++m) s2 += expf(tkv[i][m] - m0);
    float i2 = 1.0f / s2;
    for (int m = 0; m < 32; ++m) tkv[i][m] = expf(tkv[i][m] - m0) * i2;
  }
  __syncthreads();
  for (int e = tid; e < 4096; e += 256) scratch[e >> 6][e & 63] = 0.0f;
  __syncthreads();
  if (tid < 64) for (int m = 0; m < 32; ++m) scratch[tid][tki[tid][m]] = tkv[tid][m];
  __syncthreads();
  for (int e = tid; e < 4096; e += 256) Sout[e] = scratch[e >> 6][e & 63];
}

// qS[bh][j][s] = sum_i S[i][j] * qT[bh][i][s]
__global__ __launch_bounds__(256) void qs_k(const float* __restrict__ qT, const float* __restrict__ S,
                                            float* __restrict__ qS) {
  __shared__ float Sl[64][64];
  int tid = threadIdx.x;
  for (int e = tid; e < 4096; e += 256) Sl[e >> 6][e & 63] = S[e];
  __syncthreads();
  int bh = blockIdx.x;
  int s = blockIdx.y * 64 + (tid & 63);
  int jg = (tid >> 6) * 16;
  float acc[16] = {};
  const float* qb = qT + (size_t)bh * 64 * 512 + s;
  for (int i = 0; i < 64; ++i) {
    float qv = qb[i * 512];
#pragma unroll
    for (int jj = 0; jj < 16; ++jj) acc[jj] += Sl[i][jg + jj] * qv;
  }
  float* ob = qS + (size_t)bh * 64 * 512 + s;
#pragma unroll
  for (int jj = 0; jj < 16; ++jj) ob[(jg + jj) * 512] = acc[jj];
}

// per (bh,j) circular cross-correlation partials
__global__ __launch_bounds__(256) void ccor_k(const float* __restrict__ qS, const float* __restrict__ kT,
                                              float* __restrict__ part) {
  __shared__ float qr[512], kr[512];
  int tid = threadIdx.x;
  int bj = blockIdx.x;
  const float* q = qS + (size_t)bj * 512;
  const float* k = kT + (size_t)bj * 512;
  qr[tid] = q[tid]; qr[tid + 256] = q[tid + 256];
  kr[tid] = k[tid]; kr[tid + 256] = k[tid + 256];
  __syncthreads();
  int t0 = tid, t1 = tid + 256;
  float a0 = 0, a1 = 0;
  for (int s = 0; s < 512; ++s) {
    float qv = qr[s];
    a0 += qv * kr[(s - t0) & 511];
    a1 += qv * kr[(s - t1) & 511];
  }
  part[(size_t)bj * 512 + t0] = a0;
  part[(size_t)bj * 512 + t1] = a1;
}

__global__ void redmc_k(const float* __restrict__ part, float* __restrict__ mc) {
  int t = blockIdx.x * 256 + threadIdx.x;
  float s = 0;
  for (int p = 0; p < 2048; ++p) s += part[(size_t)p * 512 + t];
  mc[t] = s * (1.0f / 2048.0f);
}

// top-6 + softmax + ks fold + threefry key schedule
__global__ void top6_k(const float* __restrict__ mc, unsigned* metaU, float* tmpc) {
  if (threadIdx.x != 0 || blockIdx.x != 0) return;
  float vals[6]; int idx[6];
  for (int m = 0; m < 6; ++m) {
    float best = -1e30f; int bi = 0;
    for (int t = 0; t < 512; ++t) {
      bool skip = false;
      for (int p = 0; p < m; ++p) if (idx[p] == t) skip = true;
      if (skip) continue;
      float v = mc[t];
      if (v > best) { best = v; bi = t; }
    }
    vals[m] = best; idx[m] = bi;
  }
  float mx = vals[0], s = 0;
  for (int m = 0; m < 6; ++m) s += expf(vals[m] - mx);
  for (int m = 0; m < 6; ++m) tmpc[m] = expf(vals[m] - mx) / s;
  for (int m = 0; m < 6; ++m) {
    metaU[m] = (unsigned)idx[m];
    int ind = idx[m];
    if (ind >= 256) ind = 512 - ind;
    metaU[6 + m] = (unsigned)ind;
    unsigned kk0, kk1; tf_block(0u, 1u, 0u, (unsigned)ind, kk0, kk1);
    unsigned* kp = metaU + 24 + m * 8;
#pragma unroll
    for (int i = 0; i < 4; ++i) {
      unsigned o0, o1;
      tf_block(kk0, kk1, 0u, (unsigned)i, o0, o1);
      kp[2*i]   = o0;
      kp[2*i+1] = o1;
    }
    // key0 -> w1 (normal), key1 -> b1 (uniform), key2 -> w2 (normal), key3 -> b2 (uniform)
  }
}

// conv weights, hi-only bf16, stored PRE-SWIZZLED for conflict-free LDS use:
// short index d = kp*16384 + co*128 + slot*8 + j, where slot = chunk ^ (co&15),
// chunk = ci>>3, j = ci&7. jax source linear index e over (co,ci,kp).
// grid (2048, 2): each thread generates 8 weights. grid.y: 0 -> w1 (key0), 1 -> w2 (key2).
__global__ __launch_bounds__(256) void genw_k(float* __restrict__ ws, const unsigned* __restrict__ metaU,
                                              int sel) {
  int ks = (int)metaU[6 + sel];
  if (ks <= 1) return;
  int n = ks << 14;
  const unsigned* kp_ = metaU + 24 + sel * 8 + (blockIdx.y ? 4 : 0);
  unsigned k0 = kp_[0], k1 = kp_[1];
  unsigned short* dst = (unsigned short*)(ws + (blockIdx.y ? OFF_W2 : OFF_W1));
  int base = blockIdx.x * 256 + threadIdx.x;
#pragma unroll
  for (int jj = 0; jj < 8; ++jj) {
    int d = base + jj * 524288;
    if (d < n) {
      int kp = d >> 14, rem = d & 16383;
      int co = rem >> 7, slot = (rem >> 3) & 15, j = d & 7;
      int ci = ((slot ^ (co & 15)) << 3) + j;
      unsigned e = (unsigned)((co * 128 + ci) * ks + kp);
      float w = 0.01f * bits_to_normal(tf_bits32(k0, k1, e));
      dst[d] = f2bf(w);
    }
  }
}

__global__ void genb_k(float* __restrict__ ws, const unsigned* __restrict__ metaU, int sel) {
  int ks = (int)metaU[6 + sel];
  if (ks <= 1) return;
  int tid = threadIdx.x;
  int which = tid >> 7;     // 0: b1 (key1), 1: b2 (key3)
  int e = tid & 127;
  const unsigned* kp = metaU + 24 + sel * 8 + (which ? 6 : 2);
  float bound = (float)(1.0 / sqrt((double)(128 * ks)));
  unsigned bits = tf_bits32(kp[0], kp[1], (unsigned)e);
  float f = __uint_as_float((bits >> 9) | 0x3F800000u) - 1.0f;
  float r = f * (2.0f * bound) + (-bound);
  r = fmaxf(-bound, r);
  float* dst = ws + (which ? OFF_B2 : OFF_B1);
  dst[e] = r;
}

// ---------------- MFMA implicit-GEMM causal conv, split-K over kp (6 splits) ----------------
// partial_z[bh][t][co] = sum_{kp in [z*ks/6,(z+1)*ks/6)} sum_ci W[kp][co][ci]*xpad[257-ks+t+kp][ci]
// grid (32 bh, 4 tt of 128t, 6 z) = 768 blocks (3/CU). Block = 128t x 128co; wave wv = 128t x 32co
// (m=8 subtiles x n=2; acc = 16 ffrags = 64 VGPR). Round-8 PMC: "WRITE_SIZE" tracks the weight
// re-stream (blocks-per-co x full W), NOT store pattern — so halve the stream: 128 (bh,tt)
// readers instead of 256. Partials stored bf16 (6 buffers fit dead arena; +1 rounding, ~+0.005 err).
// Per kp one 32 KB slab staged to LDS (XOR-swizzle, conflict-free — r6 verified); prefetch kp+1.
// Epilogue: 128x128 bf16 tile (exactly 32 KB) transposed through LDS -> contiguous float4 stores.
__global__ __launch_bounds__(256) void conv_split(const unsigned short* __restrict__ src,
                                                  const unsigned short* __restrict__ wgl,
                                                  float* __restrict__ wsf,
                                                  const unsigned* __restrict__ metaU, int sel) {
  int ks = (int)metaU[6 + sel];
  if (ks <= 1) return;
  __shared__ unsigned short lds_w[128 * 128];   // 32 KB; weight slab, then epilogue transpose
  int bh = blockIdx.x, tt = blockIdx.y, z = blockIdx.z;
  unsigned short* SP = (unsigned short*)(wsf + (z < 2 ? (OFF_QS + z * M1)
                                       : z < 4 ? (OFF_SPA + (z - 2) * M1)
                                               : (OFF_SPB + (z - 4) * M1)));
  int k0 = (z * ks) / 6, k1 = ((z + 1) * ks) / 6;
  int tid = threadIdx.x;
  int lane = tid & 63, wv = tid >> 6;
  int mrow = lane & 15, quad = lane >> 4;
  int t0 = tt * 128;
  int nbase = wv * 32;                          // wave's co base (2 n-subtiles)

  ffrag zero = {0.f, 0.f, 0.f, 0.f};
  ffrag acc[8][2];
#pragma unroll
  for (int m = 0; m < 8; ++m)
#pragma unroll
    for (int n = 0; n < 2; ++n) acc[m][n] = zero;

  if (k0 < k1) {
    const float4* g4 = (const float4*)wgl;      // [kp][2048 float4]
    float4 pf[8];
    {
      const float4* gs = g4 + (size_t)k0 * 2048;
#pragma unroll
      for (int i = 0; i < 8; ++i) pf[i] = gs[i * 256 + tid];
    }
    const unsigned short* ap = src + ((size_t)(bh * 768 + 257 - ks + t0 + mrow)) * 128 + quad * 8;

    for (int kp = k0; kp < k1; ++kp) {
      __syncthreads();   // all waves done reading lds_w from previous iteration
#pragma unroll
      for (int i = 0; i < 8; ++i)
        *(float4*)((char*)lds_w + (i * 256 + tid) * 16) = pf[i];
      if (kp + 1 < k1) {
        const float4* gs = g4 + (size_t)(kp + 1) * 2048;
#pragma unroll
        for (int i = 0; i < 8; ++i) pf[i] = gs[i * 256 + tid];
      }
      __syncthreads();   // slab visible to all waves
      const unsigned short* ab = ap + (size_t)kp * 128;
#pragma unroll
      for (int kst = 0; kst < 4; ++kst) {
        bfrag b8[2];
#pragma unroll
        for (int n = 0; n < 2; ++n) {
          int co = nbase + n * 16 + mrow;
          int slot = (kst * 4 + quad) ^ mrow;
          b8[n] = *(const bfrag*)((char*)lds_w + co * 256 + slot * 16);
        }
#pragma unroll
        for (int m = 0; m < 8; ++m) {
          bfrag a = *(const bfrag*)(ab + (size_t)m * 2048 + kst * 32);
#pragma unroll
          for (int n = 0; n < 2; ++n)
            acc[m][n] = __builtin_amdgcn_mfma_f32_16x16x32_bf16(a, b8[n], acc[m][n], 0, 0, 0);
        }
      }
    }
  }

  // --- coalesced bf16 store epilogue: acc -> LDS [t_local][co] -> linear float4 stores ---
  __syncthreads();                 // done with lds_w as weight slab
#pragma unroll
  for (int m = 0; m < 8; ++m) {
#pragma unroll
    for (int n = 0; n < 2; ++n) {
      int cog = nbase + n * 16 + mrow;
#pragma unroll
      for (int r = 0; r < 4; ++r) {
        int tl = m * 16 + quad * 4 + r;
        lds_w[tl * 128 + cog] = f2bf(acc[m][n][r]);
      }
    }
  }
  __syncthreads();
  // tile is contiguous in SP: base = (bh*512 + t0)*128 shorts, 128*128 shorts = 32 KB
  float4* spv = (float4*)(SP + ((size_t)(bh * 512) + t0) * 128);
  const float4* lf4 = (const float4*)lds_w;
#pragma unroll
  for (int k = 0; k < 8; ++k)
    spv[k * 256 + tid] = lf4[k * 256 + tid];
}

// epilogue 1: h = relu(sum_z SPz + b1) -> hpadT bf16   (grid 2048, 4 elems/thread)
__global__ void epi1_k(const float* __restrict__ wsf, const float* __restrict__ bias,
                       unsigned short* __restrict__ hpad,
                       const unsigned* __restrict__ metaU, int sel) {
  int ks = (int)metaU[6 + sel];
  if (ks <= 1) return;
  const unsigned short* s0 = (const unsigned short*)(wsf + OFF_QS);
  const unsigned short* s1 = (const unsigned short*)(wsf + OFF_QS + M1);
  const unsigned short* s2 = (const unsigned short*)(wsf + OFF_SPA);
  const unsigned short* s3 = (const unsigned short*)(wsf + OFF_SPA + M1);
  const unsigned short* s4 = (const unsigned short*)(wsf + OFF_SPB);
  const unsigned short* s5 = (const unsigned short*)(wsf + OFF_SPB + M1);
  int base = blockIdx.x * 1024 + threadIdx.x;
#pragma unroll
  for (int j = 0; j < 4; ++j) {
    int e = base + j * 256;   // < 2^21 ; e = (bh*512+t)*128 + c
    int c = e & 127, t = (e >> 7) & 511, bh = e >> 16;
    float v = bf2f(s0[e]) + bf2f(s1[e]) + bf2f(s2[e]) + bf2f(s3[e]) + bf2f(s4[e]) + bf2f(s5[e]);
    v = fmaxf(v + bias[c], 0.0f);
    hpad[((size_t)(bh * 768) + 256 + t) * 128 + c] = f2bf(v);
  }
}

// epilogue 2: aggA += tc * relu(relu(sum_z SPz + b2) + v2)
__global__ void epi2_k(const float* __restrict__ wsf, const float* __restrict__ bias,
                       const unsigned short* __restrict__ v2pad, float* __restrict__ aggA,
                       const unsigned* __restrict__ metaU, const float* __restrict__ tmpc, int sel) {
  int ks = (int)metaU[6 + sel];
  if (ks <= 1) return;
  const unsigned short* s0 = (const unsigned short*)(wsf + OFF_QS);
  const unsigned short* s1 = (const unsigned short*)(wsf + OFF_QS + M1);
  const unsigned short* s2 = (const unsigned short*)(wsf + OFF_SPA);
  const unsigned short* s3 = (const unsigned short*)(wsf + OFF_SPA + M1);
  const unsigned short* s4 = (const unsigned short*)(wsf + OFF_SPB);
  const unsigned short* s5 = (const unsigned short*)(wsf + OFF_SPB + M1);
  float tc = tmpc[sel];
  int base = blockIdx.x * 1024 + threadIdx.x;
#pragma unroll
  for (int j = 0; j < 4; ++j) {
    int e = base + j * 256;
    int c = e & 127, t = (e >> 7) & 511, bh = e >> 16;
    float v = bf2f(s0[e]) + bf2f(s1[e]) + bf2f(s2[e]) + bf2f(s3[e]) + bf2f(s4[e]) + bf2f(s5[e]);
    v = fmaxf(v + bias[c], 0.0f);
    float v2 = bf2f(v2pad[((size_t)(bh * 768) + 256 + t) * 128 + c]);
    float tb = fmaxf(v + v2, 0.0f);
    aggA[((size_t)(t * 4 + (bh >> 3))) * 1024 + (bh & 7) * 128 + c] += tc * tb;
  }
}

// ks<=1 path: aggA += tc * v2   (grid 2048, 4 elems/thread)
__global__ void resid_k(const unsigned short* __restrict__ xpad, float* __restrict__ aggA,
                        const unsigned* __restrict__ metaU, const float* __restrict__ tmpc, int sel) {
  int ks = (int)metaU[6 + sel];
  if (ks > 1) return;
  float tc = tmpc[sel];
  int base = blockIdx.x * 1024 + threadIdx.x;
#pragma unroll
  for (int j = 0; j < 4; ++j) {
    int e = base + j * 256;   // < 32*512*128 = 2^21
    int c = e & 127, t = (e >> 7) & 511, bh = e >> 16;
    float v2 = bf2f(xpad[((size_t)(bh * 768) + 256 + t) * 128 + c]);
    aggA[((size_t)(t * 4 + (bh >> 3))) * 1024 + (bh & 7) * 128 + c] += tc * v2;
  }
}

// dim_cor partial: for (bh,sel): P[i][j] = sum_s qT[i][s]*kT[j][(s-t*)&511]; atomic += tc/32 * P
__global__ __launch_bounds__(256) void dimcor_k(const float* __restrict__ qT, const float* __restrict__ kT,
                                                float* __restrict__ dima, const unsigned* __restrict__ metaU,
                                                const float* __restrict__ tmpc) {
  __shared__ float qs[64][33];
  __shared__ float ksh[64][33];
  int bh = blockIdx.x, sel = blockIdx.y;
  int tstar = (int)metaU[sel];
  float scale = tmpc[sel] * (1.0f / 32.0f);
  int tid = threadIdx.x;
  int tx = tid & 15, ty = tid >> 4;
  float acc[4][4] = {};
  const float* qb = qT + (size_t)bh * 64 * 512;
  const float* kb = kT + (size_t)bh * 64 * 512;
  int ss = tid & 31, rr = tid >> 5;
  for (int s0 = 0; s0 < 512; s0 += 32) {
#pragma unroll
    for (int l = 0; l < 8; ++l) {
      int row = rr + 8 * l;
      qs[row][ss]  = qb[row * 512 + s0 + ss];
      ksh[row][ss] = kb[row * 512 + ((s0 + ss - tstar) & 511)];
    }
    __syncthreads();
#pragma unroll
    for (int s = 0; s < 32; ++s) {
      float a[4], b[4];
#pragma unroll
      for (int i = 0; i < 4; ++i) a[i] = qs[ty + 16*i][s];
#pragma unroll
      for (int j = 0; j < 4; ++j) b[j] = ksh[tx + 16*j][s];
#pragma unroll
      for (int i = 0; i < 4; ++i)
#pragma unroll
        for (int j = 0; j < 4; ++j) acc[i][j] += a[i] * b[j];
    }
    __syncthreads();
  }
#pragma unroll
  for (int i = 0; i < 4; ++i)
#pragma unroll
    for (int j = 0; j < 4; ++j)
      atomicAdd(&dima[(ty + 16*i) * 64 + tx + 16*j], acc[i][j] * scale);
}

__global__ void dsm_k(const float* __restrict__ dima, float* __restrict__ out) {
  int i = threadIdx.x;
  if (i >= 64) return;
  float mx = -1e30f;
  for (int j = 0; j < 64; ++j) mx = fmaxf(mx, 0.125f * dima[i * 64 + j]);
  float s = 0;
  for (int j = 0; j < 64; ++j) s += expf(0.125f * dima[i * 64 + j] - mx);
  float inv = 1.0f / s;
  for (int j = 0; j < 64; ++j) out[i * 64 + j] = expf(0.125f * dima[i * 64 + j] - mx) * inv;
}

extern "C" void kernel_launch(void* const* d_in, const int* in_sizes, int n_in,
                              void* d_out, int out_size, void* d_ws, size_t ws_size,
                              hipStream_t stream) {
  (void)in_sizes; (void)n_in; (void)out_size; (void)ws_size;
  const float* query  = (const float*)d_in[0];
  const float* key_in = (const float*)d_in[1];
  const float* value  = (const float*)d_in[2];
  const float* Wq = (const float*)d_in[4];
  const float* bq = (const float*)d_in[5];
  const float* Wk = (const float*)d_in[6];
  const float* bk = (const float*)d_in[7];
  const float* Wv = (const float*)d_in[8];
  const float* bv = (const float*)d_in[9];
  const float* Wo = (const float*)d_in[10];
  const float* bo = (const float*)d_in[11];
  const float* warr = (const float*)d_in[12];
  float* out = (float*)d_out;
  float* ws = (float*)d_ws;
  unsigned* metaU = (unsigned*)(ws + OFF_META);
  float* tmpc = ws + OFF_TMPC;
  unsigned short* xpad = (unsigned short*)(ws + OFF_XT);
  unsigned short* hpad = (unsigned short*)(ws + OFF_H);
  float* aggA = ws + OFF_AGGA;

  // zero: aggA (accumulated), xpad/hpad pad rows, dim_cor accum
  hipMemsetAsync(aggA, 0, (size_t)2048 * 1024 * 4, stream);
  hipMemsetAsync(xpad, 0, (size_t)32 * 768 * 128 * 2, stream);
  hipMemsetAsync(hpad, 0, (size_t)32 * 768 * 128 * 2, stream);
  hipMemsetAsync(ws + OFF_DIMA, 0, 4096 * sizeof(float), stream);

  // projections
  gemm_k<1><<<dim3(32, 8), 256, 0, stream>>>(query,  Wq, bq, ws + OFF_QT, 512);
  gemm_k<1><<<dim3(32, 8), 256, 0, stream>>>(key_in, Wk, bk, ws + OFF_KT, 512);
  gemm_k<2><<<dim3(32, 8), 256, 0, stream>>>(value,  Wv, bv, (float*)xpad, 512);
  fillw_k<<<4096, 256, 0, stream>>>(warr, xpad);

  // cos graph / ji_mat / S
  graph_k<<<1, 256, 0, stream>>>(warr, ws + OFF_S, out + 1048576 + 4096);

  // mean_corr via folded sparse-weighted circular correlation
  qs_k<<<dim3(32, 8), 256, 0, stream>>>(ws + OFF_QT, ws + OFF_S, ws + OFF_QS);
  ccor_k<<<2048, 256, 0, stream>>>(ws + OFF_QS, ws + OFF_KT, ws + OFF_PART);
  redmc_k<<<2, 256, 0, stream>>>(ws + OFF_PART, ws + OFF_MC);
  top6_k<<<1, 64, 0, stream>>>(ws + OFF_MC, metaU, tmpc);

  // temporal blocks (fixed worst-case grids; device-side ks gates the work)
  for (int sel = 0; sel < 6; ++sel) {
    genw_k<<<dim3(2048, 2), 256, 0, stream>>>(ws, metaU, sel);
    genb_k<<<1, 256, 0, stream>>>(ws, metaU, sel);
    conv_split<<<dim3(32, 4, 6), 256, 0, stream>>>(
        xpad, (unsigned short*)(ws + OFF_W1), ws, metaU, sel);
    epi1_k<<<2048, 256, 0, stream>>>(ws, ws + OFF_B1, hpad, metaU, sel);
    conv_split<<<dim3(32, 4, 6), 256, 0, stream>>>(
        hpad, (unsigned short*)(ws + OFF_W2), ws, metaU, sel);
    epi2_k<<<2048, 256, 0, stream>>>(ws, ws + OFF_B2, xpad, aggA, metaU, tmpc, sel);
    resid_k<<<2048, 256, 0, stream>>>(xpad, aggA, metaU, tmpc, sel);
  }

  // output projection (aggA is already [ (t*4+b) ][ h*128+c ])
  gemm_k<0><<<dim3(32, 8), 256, 0, stream>>>(aggA, Wo, bo, out, 1024);

  // dim_cor
  dimcor_k<<<dim3(32, 6), 256, 0, stream>>>(ws + OFF_QT, ws + OFF_KT, ws + OFF_DIMA, metaU, tmpc);
  dsm_k<<<1, 64, 0, stream>>>(ws + OFF_DIMA, out + 1048576);
}

// Round 10
// 5376.315 us; speedup vs baseline: 1.3620x; 1.0431x over previous
//
#include <hip/hip_runtime.h>
#include <hip/hip_bf16.h>
#include <math.h>

// Problem constants: T=512, B=4, H=8, D=64, BH=32, C2=128 (=2*D), d_model=512.
#define M1 (1<<20)
// ws arena (float slot offsets). Timeline: [proj/graph/ccor phase] then [conv loop] then [out gemm].
#define OFF_QT   (0)            // qT [32][64][512] fp32 (whole session)
#define OFF_KT   (1*M1)         // kT [32][64][512] fp32 (whole session)
#define OFF_XT   (2*M1)         // xpadT [32][768][128] bf16 (1.5 M1 slots) — v2 padded, t-major
#define OFF_QS   (4*M1)         // qS (dead after ccor) — reused as SP buffers in conv loop
#define OFF_PART (5*M1)         // ccor partials (dead after redmc)
#define OFF_AGGA (6*M1)         // aggA [2048][1024] fp32 (accumulated by epi2/resid)
#define OFF_H    (8*M1)         // hpadT [32][768][128] bf16 (1.5 M1 slots, conv loop)
#define OFF_W1   (10*M1)        // conv1 W bf16 swizzled (2M floats at ks=256); dead after conv1
#define OFF_SPA  (12*M1)
#define OFF_W2   (14*M1)        // conv2 W; REGENERATED after epi1 (conv1 partials borrow this slot)
#define OFF_SPB  (16*M1)
#define OFF_TAIL (18*M1)
#define OFF_B1   (OFF_TAIL)
#define OFF_B2   (OFF_TAIL+128)
#define OFF_MC   (OFF_TAIL+256)        // mean_corr[512]
#define OFF_S    (OFF_TAIL+1024)       // S [64][64]
#define OFF_DIMA (OFF_TAIL+1024+4096)  // dim_cor accum [64][64]
#define OFF_META (OFF_TAIL+1024+8192)  // u32: idx6[6], ks6[6], pad, keys@24 (48 u32)
#define OFF_TMPC (OFF_META+128)        // floats: tmp_corr[6]

// 8 bf16 split-K partial buffers (each 32*512*128 bf16 = 1M float slots), time-multiplexed:
// conv1 set may clobber W2 slot (regenerated after epi1); conv2 set clobbers dead W1 slot.
__device__ const unsigned SP_OFF[2][8] = {
  {4*M1, 5*M1, 12*M1, 13*M1, 14*M1, 15*M1, 16*M1, 17*M1},   // conv1 (which=0)
  {4*M1, 5*M1, 10*M1, 11*M1, 12*M1, 13*M1, 16*M1, 17*M1}};  // conv2 (which=1)

typedef __attribute__((ext_vector_type(8))) short bfrag;   // 8 bf16 = 4 VGPRs
typedef __attribute__((ext_vector_type(4))) float ffrag;   // MFMA C/D

__device__ __forceinline__ unsigned short f2bf(float f) {
  __hip_bfloat16 h = __float2bfloat16(f);   // RNE
  return *reinterpret_cast<unsigned short*>(&h);
}
__device__ __forceinline__ float bf2f(unsigned short u) {
  return __uint_as_float(((unsigned)u) << 16);
}

// ---------------- Threefry-2x32 core ----------------
__device__ __forceinline__ void tf_block(unsigned k0, unsigned k1, unsigned x0, unsigned x1,
                                         unsigned& o0, unsigned& o1) {
  unsigned k2 = k0 ^ k1 ^ 0x1BD11BDAu;
  x0 += k0; x1 += k1;
#define TFR(r) { x0 += x1; x1 = (x1<<(r))|(x1>>(32-(r))); x1 ^= x0; }
  TFR(13) TFR(15) TFR(26) TFR(6)   x0 += k1; x1 += k2 + 1u;
  TFR(17) TFR(29) TFR(16) TFR(24)  x0 += k2; x1 += k0 + 2u;
  TFR(13) TFR(15) TFR(26) TFR(6)   x0 += k0; x1 += k1 + 3u;
  TFR(17) TFR(29) TFR(16) TFR(24)  x0 += k1; x1 += k2 + 4u;
  TFR(13) TFR(15) TFR(26) TFR(6)   x0 += k2; x1 += k0 + 5u;
#undef TFR
  o0 = x0; o1 = x1;
}

// jax_threefry_partitionable (default since 0.4.36): counter (0, e), result = out0^out1.
__device__ __forceinline__ unsigned tf_bits32(unsigned k0, unsigned k1, unsigned e) {
  unsigned o0, o1;
  tf_block(k0, k1, 0u, e, o0, o1);
  return o0 ^ o1;
}

// Giles/XLA erfinv (f32)
__device__ __forceinline__ float erfinv32(float x) {
  float w = -log1pf(-x*x);
  float p;
  if (w < 5.0f) {
    w = w - 2.5f;
    p = 2.81022636e-08f;
    p = fmaf(p, w, 3.43273939e-07f);
    p = fmaf(p, w, -3.5233877e-06f);
    p = fmaf(p, w, -4.39150654e-06f);
    p = fmaf(p, w, 0.00021858087f);
    p = fmaf(p, w, -0.00125372503f);
    p = fmaf(p, w, -0.00417768164f);
    p = fmaf(p, w, 0.246640727f);
    p = fmaf(p, w, 1.50140941f);
  } else {
    w = sqrtf(w) - 3.0f;
    p = -0.000200214257f;
    p = fmaf(p, w, 0.000100950558f);
    p = fmaf(p, w, 0.00134934322f);
    p = fmaf(p, w, -0.00367342844f);
    p = fmaf(p, w, 0.00573950773f);
    p = fmaf(p, w, -0.0076224613f);
    p = fmaf(p, w, 0.00943887047f);
    p = fmaf(p, w, 1.00167406f);
    p = fmaf(p, w, 2.83297682f);
  }
  return p * x;
}

__device__ __forceinline__ float bits_to_normal(unsigned b) {
  float f = __uint_as_float((b >> 9) | 0x3F800000u) - 1.0f;
  const float lo = -0.99999994f;
  float u = fmaxf(lo, f * 2.0f + lo);
  return 1.4142135623730951f * erfinv32(u);
}

// ---------------- fp32 GEMM: C[2048xN=512] = A[2048xK] @ B[512xK]^T + bias ----------------
// MODE 0: row-major fp32 out. MODE 1: scatter fp32 to qT/kT [bh][d][t]. MODE 2: scatter bf16 to xpadT.
template<int MODE>
__global__ __launch_bounds__(256) void gemm_k(const float* __restrict__ A, const float* __restrict__ B,
                                              const float* __restrict__ bias, float* __restrict__ Cout,
                                              int K) {
  __shared__ float As[16][65];
  __shared__ float Bs[16][65];
  int tid = threadIdx.x;
  int tx = tid & 15, ty = tid >> 4;
  int rBase = blockIdx.x * 64;
  int cBase = blockIdx.y * 64;
  float acc[4][4] = {};
  int m = tid & 63, kq = tid >> 6;
  for (int kk = 0; kk < K; kk += 16) {
    float4 av = *(const float4*)(A + (size_t)(rBase + m) * K + kk + kq * 4);
    float4 bv = *(const float4*)(B + (size_t)(cBase + m) * K + kk + kq * 4);
    As[kq*4+0][m] = av.x; As[kq*4+1][m] = av.y; As[kq*4+2][m] = av.z; As[kq*4+3][m] = av.w;
    Bs[kq*4+0][m] = bv.x; Bs[kq*4+1][m] = bv.y; Bs[kq*4+2][m] = bv.z; Bs[kq*4+3][m] = bv.w;
    __syncthreads();
#pragma unroll
    for (int k = 0; k < 16; ++k) {
      float a[4], b[4];
#pragma unroll
      for (int i = 0; i < 4; ++i) a[i] = As[k][ty + 16*i];
#pragma unroll
      for (int j = 0; j < 4; ++j) b[j] = Bs[k][tx + 16*j];
#pragma unroll
      for (int i = 0; i < 4; ++i)
#pragma unroll
        for (int j = 0; j < 4; ++j) acc[i][j] += a[i] * b[j];
    }
    __syncthreads();
  }
#pragma unroll
  for (int i = 0; i < 4; ++i) {
    int r = rBase + ty + 16*i;
    int t = r >> 2, bb = r & 3;
#pragma unroll
    for (int j = 0; j < 4; ++j) {
      int c = cBase + tx + 16*j;
      float v = acc[i][j] + bias[c];
      if (MODE == 0) {
        Cout[(size_t)r * 512 + c] = v;
      } else if (MODE == 1) {
        int h = c >> 6, d = c & 63;
        Cout[((size_t)(bb*8 + h) * 64 + d) * 512 + t] = v;
      } else {
        int h = c >> 6, d = c & 63;
        ((unsigned short*)Cout)[((size_t)((bb*8 + h) * 768) + 256 + t) * 128 + d] = f2bf(v);
      }
    }
  }
}

// fill xpadT channels 64..127: xpadT[bh][256+t][64+dd] = bf16(w[dd][bh])
__global__ void fillw_k(const float* __restrict__ warr, unsigned short* __restrict__ xpad) {
  int e = blockIdx.x * 256 + threadIdx.x;   // < 32*512*64 = 2^20
  int dd = e & 63, t = (e >> 6) & 511, bh = e >> 15;
  xpad[((size_t)(bh * 768) + 256 + t) * 128 + 64 + dd] = f2bf(warr[dd * 32 + bh]);
}

// cos-sim graph: ji_mat (output), top-32 per row, tk_w softmax, S scatter matrix
__global__ __launch_bounds__(256) void graph_k(const float* __restrict__ warr,
                                               float* __restrict__ Sout, float* __restrict__ jiout) {
  __shared__ float wl[64][32];
  __shared__ float cosl[64][65];
  __shared__ float scratch[64][64];
  __shared__ float nrm[64];
  __shared__ float tkv[64][32];
  __shared__ int   tki[64][32];
  int tid = threadIdx.x;
  for (int e = tid; e < 64*32; e += 256) wl[e >> 5][e & 31] = warr[e];
  __syncthreads();
  {
    int i = tid >> 2;
    for (int jj = 0; jj < 16; ++jj) {
      int j = (tid & 3) * 16 + jj;
      float s = 0;
      for (int n = 0; n < 32; ++n) s += wl[i][n] * wl[j][n];
      cosl[i][j] = s;
    }
  }
  __syncthreads();
  if (tid < 64) nrm[tid] = sqrtf(cosl[tid][tid]);
  __syncthreads();
  {
    int i = tid >> 2;
    for (int jj = 0; jj < 16; ++jj) {
      int j = (tid & 3) * 16 + jj;
      float v = cosl[i][j] / (nrm[i] * nrm[j]);
      cosl[i][j] = v;
      scratch[i][j] = v;
    }
  }
  __syncthreads();
  if (tid < 64) {
    int i = tid;
    float mx = -1e30f;
    for (int j = 0; j < 64; ++j) mx = fmaxf(mx, cosl[i][j]);
    float sum = 0;
    for (int j = 0; j < 64; ++j) sum += expf(cosl[i][j] - mx);
    float inv = 1.0f / sum;
    for (int j = 0; j < 64; ++j) jiout[i * 64 + j] = expf(cosl[i][j] - mx) * inv;
    for (int m = 0; m < 32; ++m) {
      float best = -1e30f; int bi = 0;
      for (int j = 0; j < 64; ++j) { float v = scratch[i][j]; if (v > best) { best = v; bi = j; } }
      tkv[i][m] = best; tki[i][m] = bi; scratch[i][bi] = -1e30f;
    }
    float m0 = tkv[i][0], s2 = 0;
    for (int m = 0; m < 32; ++m) s2 += expf(tkv[i][m] - m0);
    float i2 = 1.0f / s2;
    for (int m = 0; m < 32; ++m) tkv[i][m] = expf(tkv[i][m] - m0) * i2;
  }
  __syncthreads();
  for (int e = tid; e < 4096; e += 256) scratch[e >> 6][e & 63] = 0.0f;
  __syncthreads();
  if (tid < 64) for (int m = 0; m < 32; ++m) scratch[tid][tki[tid][m]] = tkv[tid][m];
  __syncthreads();
  for (int e = tid; e < 4096; e += 256) Sout[e] = scratch[e >> 6][e & 63];
}

// qS[bh][j][s] = sum_i S[i][j] * qT[bh][i][s]
__global__ __launch_bounds__(256) void qs_k(const float* __restrict__ qT, const float* __restrict__ S,
                                            float* __restrict__ qS) {
  __shared__ float Sl[64][64];
  int tid = threadIdx.x;
  for (int e = tid; e < 4096; e += 256) Sl[e >> 6][e & 63] = S[e];
  __syncthreads();
  int bh = blockIdx.x;
  int s = blockIdx.y * 64 + (tid & 63);
  int jg = (tid >> 6) * 16;
  float acc[16] = {};
  const float* qb = qT + (size_t)bh * 64 * 512 + s;
  for (int i = 0; i < 64; ++i) {
    float qv = qb[i * 512];
#pragma unroll
    for (int jj = 0; jj < 16; ++jj) acc[jj] += Sl[i][jg + jj] * qv;
  }
  float* ob = qS + (size_t)bh * 64 * 512 + s;
#pragma unroll
  for (int jj = 0; jj < 16; ++jj) ob[(jg + jj) * 512] = acc[jj];
}

// per (bh,j) circular cross-correlation partials
__global__ __launch_bounds__(256) void ccor_k(const float* __restrict__ qS, const float* __restrict__ kT,
                                              float* __restrict__ part) {
  __shared__ float qr[512], kr[512];
  int tid = threadIdx.x;
  int bj = blockIdx.x;
  const float* q = qS + (size_t)bj * 512;
  const float* k = kT + (size_t)bj * 512;
  qr[tid] = q[tid]; qr[tid + 256] = q[tid + 256];
  kr[tid] = k[tid]; kr[tid + 256] = k[tid + 256];
  __syncthreads();
  int t0 = tid, t1 = tid + 256;
  float a0 = 0, a1 = 0;
  for (int s = 0; s < 512; ++s) {
    float qv = qr[s];
    a0 += qv * kr[(s - t0) & 511];
    a1 += qv * kr[(s - t1) & 511];
  }
  part[(size_t)bj * 512 + t0] = a0;
  part[(size_t)bj * 512 + t1] = a1;
}

__global__ void redmc_k(const float* __restrict__ part, float* __restrict__ mc) {
  int t = blockIdx.x * 256 + threadIdx.x;
  float s = 0;
  for (int p = 0; p < 2048; ++p) s += part[(size_t)p * 512 + t];
  mc[t] = s * (1.0f / 2048.0f);
}

// top-6 + softmax + ks fold + threefry key schedule
__global__ void top6_k(const float* __restrict__ mc, unsigned* metaU, float* tmpc) {
  if (threadIdx.x != 0 || blockIdx.x != 0) return;
  float vals[6]; int idx[6];
  for (int m = 0; m < 6; ++m) {
    float best = -1e30f; int bi = 0;
    for (int t = 0; t < 512; ++t) {
      bool skip = false;
      for (int p = 0; p < m; ++p) if (idx[p] == t) skip = true;
      if (skip) continue;
      float v = mc[t];
      if (v > best) { best = v; bi = t; }
    }
    vals[m] = best; idx[m] = bi;
  }
  float mx = vals[0], s = 0;
  for (int m = 0; m < 6; ++m) s += expf(vals[m] - mx);
  for (int m = 0; m < 6; ++m) tmpc[m] = expf(vals[m] - mx) / s;
  for (int m = 0; m < 6; ++m) {
    metaU[m] = (unsigned)idx[m];
    int ind = idx[m];
    if (ind >= 256) ind = 512 - ind;
    metaU[6 + m] = (unsigned)ind;
    unsigned kk0, kk1; tf_block(0u, 1u, 0u, (unsigned)ind, kk0, kk1);
    unsigned* kp = metaU + 24 + m * 8;
#pragma unroll
    for (int i = 0; i < 4; ++i) {
      unsigned o0, o1;
      tf_block(kk0, kk1, 0u, (unsigned)i, o0, o1);
      kp[2*i]   = o0;
      kp[2*i+1] = o1;
    }
    // key0 -> w1 (normal), key1 -> b1 (uniform), key2 -> w2 (normal), key3 -> b2 (uniform)
  }
}

// conv weights, hi-only bf16, stored PRE-SWIZZLED for conflict-free LDS use:
// short index d = kp*16384 + co*128 + slot*8 + j, where slot = chunk ^ (co&15),
// chunk = ci>>3, j = ci&7. jax source linear index e over (co,ci,kp).
// grid 2048, each thread generates 8 weights. which: 0 -> W1 (key0), 1 -> W2 (key2).
__global__ __launch_bounds__(256) void genw_k(float* __restrict__ ws, const unsigned* __restrict__ metaU,
                                              int sel, int which) {
  int ks = (int)metaU[6 + sel];
  if (ks <= 1) return;
  int n = ks << 14;
  const unsigned* kp_ = metaU + 24 + sel * 8 + (which ? 4 : 0);
  unsigned k0 = kp_[0], k1 = kp_[1];
  unsigned short* dst = (unsigned short*)(ws + (which ? OFF_W2 : OFF_W1));
  int base = blockIdx.x * 256 + threadIdx.x;
#pragma unroll
  for (int jj = 0; jj < 8; ++jj) {
    int d = base + jj * 524288;
    if (d < n) {
      int kp = d >> 14, rem = d & 16383;
      int co = rem >> 7, slot = (rem >> 3) & 15, j = d & 7;
      int ci = ((slot ^ (co & 15)) << 3) + j;
      unsigned e = (unsigned)((co * 128 + ci) * ks + kp);
      float w = 0.01f * bits_to_normal(tf_bits32(k0, k1, e));
      dst[d] = f2bf(w);
    }
  }
}

__global__ void genb_k(float* __restrict__ ws, const unsigned* __restrict__ metaU, int sel) {
  int ks = (int)metaU[6 + sel];
  if (ks <= 1) return;
  int tid = threadIdx.x;
  int which = tid >> 7;     // 0: b1 (key1), 1: b2 (key3)
  int e = tid & 127;
  const unsigned* kp = metaU + 24 + sel * 8 + (which ? 6 : 2);
  float bound = (float)(1.0 / sqrt((double)(128 * ks)));
  unsigned bits = tf_bits32(kp[0], kp[1], (unsigned)e);
  float f = __uint_as_float((bits >> 9) | 0x3F800000u) - 1.0f;
  float r = f * (2.0f * bound) + (-bound);
  r = fmaxf(-bound, r);
  float* dst = ws + (which ? OFF_B2 : OFF_B1);
  dst[e] = r;
}

// ---------------- MFMA implicit-GEMM causal conv, split-K over kp (8 splits) ----------------
// partial_z[bh][t][co] = sum_{kp in [z*ks/8,(z+1)*ks/8)} sum_ci W[kp][co][ci]*xpad[257-ks+t+kp][ci]
// grid (32 bh, 2 tt of 256t, 8 z) = 512 blocks (2/CU). Block = 256t x 128co; wave = 256t x 32co
// (m=16 subtiles x n=2; acc = 32 ffrags = 128 VGPR; __launch_bounds__(256,2) caps at 256).
// Traffic model (r8/r9 verified): fabric bytes = (#(bh,tt) readers) x full W. 64 readers here
// vs 128 in r9 -> 0.54 GB/conv. Partials bf16, 8 buffers time-multiplexed over dead W slots
// (SP_OFF table; W2 regenerated after epi1). LDS slab XOR-swizzle conflict-free (r6); prefetch kp+1.
// Epilogue: 256x128 bf16 tile transposed through the 32 KB LDS in two 128t passes -> contiguous
// float4 stores.
__global__ __launch_bounds__(256, 2) void conv_split(const unsigned short* __restrict__ src,
                                                     const unsigned short* __restrict__ wgl,
                                                     float* __restrict__ wsf,
                                                     const unsigned* __restrict__ metaU,
                                                     int sel, int which) {
  int ks = (int)metaU[6 + sel];
  if (ks <= 1) return;
  __shared__ unsigned short lds_w[128 * 128];   // 32 KB; weight slab, then epilogue transpose
  int bh = blockIdx.x, tt = blockIdx.y, z = blockIdx.z;
  unsigned short* SP = (unsigned short*)(wsf + SP_OFF[which][z]);
  int k0 = (z * ks) / 8, k1 = ((z + 1) * ks) / 8;
  int tid = threadIdx.x;
  int lane = tid & 63, wv = tid >> 6;
  int mrow = lane & 15, quad = lane >> 4;
  int t0 = tt * 256;
  int nbase = wv * 32;                          // wave's co base (2 n-subtiles)

  ffrag zero = {0.f, 0.f, 0.f, 0.f};
  ffrag acc[16][2];
#pragma unroll
  for (int m = 0; m < 16; ++m)
#pragma unroll
    for (int n = 0; n < 2; ++n) acc[m][n] = zero;

  if (k0 < k1) {
    const float4* g4 = (const float4*)wgl;      // [kp][2048 float4]
    float4 pf[8];
    {
      const float4* gs = g4 + (size_t)k0 * 2048;
#pragma unroll
      for (int i = 0; i < 8; ++i) pf[i] = gs[i * 256 + tid];
    }
    const unsigned short* ap = src + ((size_t)(bh * 768 + 257 - ks + t0 + mrow)) * 128 + quad * 8;

    for (int kp = k0; kp < k1; ++kp) {
      __syncthreads();   // all waves done reading lds_w from previous iteration
#pragma unroll
      for (int i = 0; i < 8; ++i)
        *(float4*)((char*)lds_w + (i * 256 + tid) * 16) = pf[i];
      if (kp + 1 < k1) {
        const float4* gs = g4 + (size_t)(kp + 1) * 2048;
#pragma unroll
        for (int i = 0; i < 8; ++i) pf[i] = gs[i * 256 + tid];
      }
      __syncthreads();   // slab visible to all waves
      const unsigned short* ab = ap + (size_t)kp * 128;
#pragma unroll
      for (int kst = 0; kst < 4; ++kst) {
        bfrag b8[2];
#pragma unroll
        for (int n = 0; n < 2; ++n) {
          int co = nbase + n * 16 + mrow;
          int slot = (kst * 4 + quad) ^ mrow;
          b8[n] = *(const bfrag*)((char*)lds_w + co * 256 + slot * 16);
        }
#pragma unroll
        for (int m = 0; m < 16; ++m) {
          bfrag a = *(const bfrag*)(ab + (size_t)m * 2048 + kst * 32);
#pragma unroll
          for (int n = 0; n < 2; ++n)
            acc[m][n] = __builtin_amdgcn_mfma_f32_16x16x32_bf16(a, b8[n], acc[m][n], 0, 0, 0);
        }
      }
    }
  }

  // --- coalesced bf16 store epilogue: two 128t passes through 32 KB LDS ---
#pragma unroll
  for (int half = 0; half < 2; ++half) {
    __syncthreads();
#pragma unroll
    for (int m = 0; m < 8; ++m) {
      int mg = half * 8 + m;
#pragma unroll
      for (int n = 0; n < 2; ++n) {
        int cog = nbase + n * 16 + mrow;
#pragma unroll
        for (int r = 0; r < 4; ++r) {
          int tl = m * 16 + quad * 4 + r;
          lds_w[tl * 128 + cog] = f2bf(acc[mg][n][r]);
        }
      }
    }
    __syncthreads();
    // 128x128 shorts = 32 KB contiguous in SP at (bh*512 + t0 + half*128)*128
    float4* spv = (float4*)(SP + ((size_t)(bh * 512) + t0 + half * 128) * 128);
    const float4* lf4 = (const float4*)lds_w;
#pragma unroll
    for (int k = 0; k < 8; ++k)
      spv[k * 256 + tid] = lf4[k * 256 + tid];
  }
}

// epilogue 1: h = relu(sum_z SPz + b1) -> hpadT bf16   (grid 2048, 4 elems/thread)
__global__ void epi1_k(const float* __restrict__ wsf, const float* __restrict__ bias,
                       unsigned short* __restrict__ hpad,
                       const unsigned* __restrict__ metaU, int sel) {
  int ks = (int)metaU[6 + sel];
  if (ks <= 1) return;
  int base = blockIdx.x * 1024 + threadIdx.x;
#pragma unroll
  for (int j = 0; j < 4; ++j) {
    int e = base + j * 256;   // < 2^21 ; e = (bh*512+t)*128 + c
    int c = e & 127, t = (e >> 7) & 511, bh = e >> 16;
    float v = 0.0f;
#pragma unroll
    for (int z = 0; z < 8; ++z)
      v += bf2f(((const unsigned short*)(wsf + SP_OFF[0][z]))[e]);
    v = fmaxf(v + bias[c], 0.0f);
    hpad[((size_t)(bh * 768) + 256 + t) * 128 + c] = f2bf(v);
  }
}

// epilogue 2: aggA += tc * relu(relu(sum_z SPz + b2) + v2)
__global__ void epi2_k(const float* __restrict__ wsf, const float* __restrict__ bias,
                       const unsigned short* __restrict__ v2pad, float* __restrict__ aggA,
                       const unsigned* __restrict__ metaU, const float* __restrict__ tmpc, int sel) {
  int ks = (int)metaU[6 + sel];
  if (ks <= 1) return;
  float tc = tmpc[sel];
  int base = blockIdx.x * 1024 + threadIdx.x;
#pragma unroll
  for (int j = 0; j < 4; ++j) {
    int e = base + j * 256;
    int c = e & 127, t = (e >> 7) & 511, bh = e >> 16;
    float v = 0.0f;
#pragma unroll
    for (int z = 0; z < 8; ++z)
      v += bf2f(((const unsigned short*)(wsf + SP_OFF[1][z]))[e]);
    v = fmaxf(v + bias[c], 0.0f);
    float v2 = bf2f(v2pad[((size_t)(bh * 768) + 256 + t) * 128 + c]);
    float tb = fmaxf(v + v2, 0.0f);
    aggA[((size_t)(t * 4 + (bh >> 3))) * 1024 + (bh & 7) * 128 + c] += tc * tb;
  }
}

// ks<=1 path: aggA += tc * v2   (grid 2048, 4 elems/thread)
__global__ void resid_k(const unsigned short* __restrict__ xpad, float* __restrict__ aggA,
                        const unsigned* __restrict__ metaU, const float* __restrict__ tmpc, int sel) {
  int ks = (int)metaU[6 + sel];
  if (ks > 1) return;
  float tc = tmpc[sel];
  int base = blockIdx.x * 1024 + threadIdx.x;
#pragma unroll
  for (int j = 0; j < 4; ++j) {
    int e = base + j * 256;   // < 32*512*128 = 2^21
    int c = e & 127, t = (e >> 7) & 511, bh = e >> 16;
    float v2 = bf2f(xpad[((size_t)(bh * 768) + 256 + t) * 128 + c]);
    aggA[((size_t)(t * 4 + (bh >> 3))) * 1024 + (bh & 7) * 128 + c] += tc * v2;
  }
}

// dim_cor partial: for (bh,sel): P[i][j] = sum_s qT[i][s]*kT[j][(s-t*)&511]; atomic += tc/32 * P
__global__ __launch_bounds__(256) void dimcor_k(const float* __restrict__ qT, const float* __restrict__ kT,
                                                float* __restrict__ dima, const unsigned* __restrict__ metaU,
                                                const float* __restrict__ tmpc) {
  __shared__ float qs[64][33];
  __shared__ float ksh[64][33];
  int bh = blockIdx.x, sel = blockIdx.y;
  int tstar = (int)metaU[sel];
  float scale = tmpc[sel] * (1.0f / 32.0f);
  int tid = threadIdx.x;
  int tx = tid & 15, ty = tid >> 4;
  float acc[4][4] = {};
  const float* qb = qT + (size_t)bh * 64 * 512;
  const float* kb = kT + (size_t)bh * 64 * 512;
  int ss = tid & 31, rr = tid >> 5;
  for (int s0 = 0; s0 < 512; s0 += 32) {
#pragma unroll
    for (int l = 0; l < 8; ++l) {
      int row = rr + 8 * l;
      qs[row][ss]  = qb[row * 512 + s0 + ss];
      ksh[row][ss] = kb[row * 512 + ((s0 + ss - tstar) & 511)];
    }
    __syncthreads();
#pragma unroll
    for (int s = 0; s < 32; ++s) {
      float a[4], b[4];
#pragma unroll
      for (int i = 0; i < 4; ++i) a[i] = qs[ty + 16*i][s];
#pragma unroll
      for (int j = 0; j < 4; ++j) b[j] = ksh[tx + 16*j][s];
#pragma unroll
      for (int i = 0; i < 4; ++i)
#pragma unroll
        for (int j = 0; j < 4; ++j) acc[i][j] += a[i] * b[j];
    }
    __syncthreads();
  }
#pragma unroll
  for (int i = 0; i < 4; ++i)
#pragma unroll
    for (int j = 0; j < 4; ++j)
      atomicAdd(&dima[(ty + 16*i) * 64 + tx + 16*j], acc[i][j] * scale);
}

__global__ void dsm_k(const float* __restrict__ dima, float* __restrict__ out) {
  int i = threadIdx.x;
  if (i >= 64) return;
  float mx = -1e30f;
  for (int j = 0; j < 64; ++j) mx = fmaxf(mx, 0.125f * dima[i * 64 + j]);
  float s = 0;
  for (int j = 0; j < 64; ++j) s += expf(0.125f * dima[i * 64 + j] - mx);
  float inv = 1.0f / s;
  for (int j = 0; j < 64; ++j) out[i * 64 + j] = expf(0.125f * dima[i * 64 + j] - mx) * inv;
}

extern "C" void kernel_launch(void* const* d_in, const int* in_sizes, int n_in,
                              void* d_out, int out_size, void* d_ws, size_t ws_size,
                              hipStream_t stream) {
  (void)in_sizes; (void)n_in; (void)out_size; (void)ws_size;
  const float* query  = (const float*)d_in[0];
  const float* key_in = (const float*)d_in[1];
  const float* value  = (const float*)d_in[2];
  const float* Wq = (const float*)d_in[4];
  const float* bq = (const float*)d_in[5];
  const float* Wk = (const float*)d_in[6];
  const float* bk = (const float*)d_in[7];
  const float* Wv = (const float*)d_in[8];
  const float* bv = (const float*)d_in[9];
  const float* Wo = (const float*)d_in[10];
  const float* bo = (const float*)d_in[11];
  const float* warr = (const float*)d_in[12];
  float* out = (float*)d_out;
  float* ws = (float*)d_ws;
  unsigned* metaU = (unsigned*)(ws + OFF_META);
  float* tmpc = ws + OFF_TMPC;
  unsigned short* xpad = (unsigned short*)(ws + OFF_XT);
  unsigned short* hpad = (unsigned short*)(ws + OFF_H);
  float* aggA = ws + OFF_AGGA;

  // zero: aggA (accumulated), xpad/hpad pad rows, dim_cor accum
  hipMemsetAsync(aggA, 0, (size_t)2048 * 1024 * 4, stream);
  hipMemsetAsync(xpad, 0, (size_t)32 * 768 * 128 * 2, stream);
  hipMemsetAsync(hpad, 0, (size_t)32 * 768 * 128 * 2, stream);
  hipMemsetAsync(ws + OFF_DIMA, 0, 4096 * sizeof(float), stream);

  // projections
  gemm_k<1><<<dim3(32, 8), 256, 0, stream>>>(query,  Wq, bq, ws + OFF_QT, 512);
  gemm_k<1><<<dim3(32, 8), 256, 0, stream>>>(key_in, Wk, bk, ws + OFF_KT, 512);
  gemm_k<2><<<dim3(32, 8), 256, 0, stream>>>(value,  Wv, bv, (float*)xpad, 512);
  fillw_k<<<4096, 256, 0, stream>>>(warr, xpad);

  // cos graph / ji_mat / S
  graph_k<<<1, 256, 0, stream>>>(warr, ws + OFF_S, out + 1048576 + 4096);

  // mean_corr via folded sparse-weighted circular correlation
  qs_k<<<dim3(32, 8), 256, 0, stream>>>(ws + OFF_QT, ws + OFF_S, ws + OFF_QS);
  ccor_k<<<2048, 256, 0, stream>>>(ws + OFF_QS, ws + OFF_KT, ws + OFF_PART);
  redmc_k<<<2, 256, 0, stream>>>(ws + OFF_PART, ws + OFF_MC);
  top6_k<<<1, 64, 0, stream>>>(ws + OFF_MC, metaU, tmpc);

  // temporal blocks (fixed worst-case grids; device-side ks gates the work).
  // Per sel: genW1 -> conv1 (partials may clobber W2 slot) -> epi1 -> genW2 -> conv2
  // (partials clobber dead W1 slot) -> epi2 -> resid.
  for (int sel = 0; sel < 6; ++sel) {
    genw_k<<<2048, 256, 0, stream>>>(ws, metaU, sel, 0);
    genb_k<<<1, 256, 0, stream>>>(ws, metaU, sel);
    conv_split<<<dim3(32, 2, 8), 256, 0, stream>>>(
        xpad, (unsigned short*)(ws + OFF_W1), ws, metaU, sel, 0);
    epi1_k<<<2048, 256, 0, stream>>>(ws, ws + OFF_B1, hpad, metaU, sel);
    genw_k<<<2048, 256, 0, stream>>>(ws, metaU, sel, 1);
    conv_split<<<dim3(32, 2, 8), 256, 0, stream>>>(
        hpad, (unsigned short*)(ws + OFF_W2), ws, metaU, sel, 1);
    epi2_k<<<2048, 256, 0, stream>>>(ws, ws + OFF_B2, xpad, aggA, metaU, tmpc, sel);
    resid_k<<<2048, 256, 0, stream>>>(xpad, aggA, metaU, tmpc, sel);
  }

  // output projection (aggA is already [ (t*4+b) ][ h*128+c ])
  gemm_k<0><<<dim3(32, 8), 256, 0, stream>>>(aggA, Wo, bo, out, 1024);

  // dim_cor
  dimcor_k<<<dim3(32, 6), 256, 0, stream>>>(ws + OFF_QT, ws + OFF_KT, ws + OFF_DIMA, metaU, tmpc);
  dsm_k<<<1, 64, 0, stream>>>(ws + OFF_DIMA, out + 1048576);
}

// Round 11
// 2157.349 us; speedup vs baseline: 3.3941x; 2.4921x over previous
//
#include <hip/hip_runtime.h>
#include <hip/hip_bf16.h>
#include <math.h>

// Problem constants: T=512, B=4, H=8, D=64, BH=32, C2=128 (=2*D), d_model=512.
#define M1 (1<<20)
// ws arena (float slot offsets). Timeline: [proj/graph/ccor phase] then [conv loop] then [out gemm].
#define OFF_QT   (0)            // qT [32][64][512] fp32 (whole session)
#define OFF_KT   (1*M1)         // kT [32][64][512] fp32 (whole session)
#define OFF_XT   (2*M1)         // xpadT [32][768][128] bf16 (1.5 M1 slots) — v2 padded, t-major
#define OFF_QS   (4*M1)         // qS (dead after ccor) — reused as SP buffers in conv loop
#define OFF_PART (5*M1)         // ccor partials (dead after redmc)
#define OFF_AGGA (6*M1)         // aggA [2048][1024] fp32 (accumulated by epi2/resid)
#define OFF_H    (8*M1)         // hpadT [32][768][128] bf16 (1.5 M1 slots, conv loop)
#define OFF_W1   (10*M1)        // conv1 W bf16 swizzled (2M floats at ks=256); dead after conv1
#define OFF_SPA  (12*M1)
#define OFF_W2   (14*M1)        // conv2 W; REGENERATED after epi1 (conv1 partials borrow this slot)
#define OFF_SPB  (16*M1)
#define OFF_TAIL (18*M1)
#define OFF_B1   (OFF_TAIL)
#define OFF_B2   (OFF_TAIL+128)
#define OFF_MC   (OFF_TAIL+256)        // mean_corr[512]
#define OFF_S    (OFF_TAIL+1024)       // S [64][64]
#define OFF_DIMA (OFF_TAIL+1024+4096)  // dim_cor accum [64][64]
#define OFF_META (OFF_TAIL+1024+8192)  // u32: idx6[6], ks6[6], pad, keys@24 (48 u32)
#define OFF_TMPC (OFF_META+128)        // floats: tmp_corr[6]

// 8 bf16 split-K partial buffers (each 32*512*128 bf16 = 1M float slots), time-multiplexed:
// conv1 set may clobber W2 slot (regenerated after epi1); conv2 set clobbers dead W1 slot.
__device__ const unsigned SP_OFF[2][8] = {
  {4*M1, 5*M1, 12*M1, 13*M1, 14*M1, 15*M1, 16*M1, 17*M1},   // conv1 (which=0)
  {4*M1, 5*M1, 10*M1, 11*M1, 12*M1, 13*M1, 16*M1, 17*M1}};  // conv2 (which=1)

typedef __attribute__((ext_vector_type(8))) short bfrag;   // 8 bf16 = 4 VGPRs
typedef __attribute__((ext_vector_type(4))) float ffrag;   // MFMA C/D

__device__ __forceinline__ unsigned short f2bf(float f) {
  __hip_bfloat16 h = __float2bfloat16(f);   // RNE
  return *reinterpret_cast<unsigned short*>(&h);
}
__device__ __forceinline__ float bf2f(unsigned short u) {
  return __uint_as_float(((unsigned)u) << 16);
}

// ---------------- Threefry-2x32 core ----------------
__device__ __forceinline__ void tf_block(unsigned k0, unsigned k1, unsigned x0, unsigned x1,
                                         unsigned& o0, unsigned& o1) {
  unsigned k2 = k0 ^ k1 ^ 0x1BD11BDAu;
  x0 += k0; x1 += k1;
#define TFR(r) { x0 += x1; x1 = (x1<<(r))|(x1>>(32-(r))); x1 ^= x0; }
  TFR(13) TFR(15) TFR(26) TFR(6)   x0 += k1; x1 += k2 + 1u;
  TFR(17) TFR(29) TFR(16) TFR(24)  x0 += k2; x1 += k0 + 2u;
  TFR(13) TFR(15) TFR(26) TFR(6)   x0 += k0; x1 += k1 + 3u;
  TFR(17) TFR(29) TFR(16) TFR(24)  x0 += k1; x1 += k2 + 4u;
  TFR(13) TFR(15) TFR(26) TFR(6)   x0 += k2; x1 += k0 + 5u;
#undef TFR
  o0 = x0; o1 = x1;
}

// jax_threefry_partitionable (default since 0.4.36): counter (0, e), result = out0^out1.
__device__ __forceinline__ unsigned tf_bits32(unsigned k0, unsigned k1, unsigned e) {
  unsigned o0, o1;
  tf_block(k0, k1, 0u, e, o0, o1);
  return o0 ^ o1;
}

// Giles/XLA erfinv (f32)
__device__ __forceinline__ float erfinv32(float x) {
  float w = -log1pf(-x*x);
  float p;
  if (w < 5.0f) {
    w = w - 2.5f;
    p = 2.81022636e-08f;
    p = fmaf(p, w, 3.43273939e-07f);
    p = fmaf(p, w, -3.5233877e-06f);
    p = fmaf(p, w, -4.39150654e-06f);
    p = fmaf(p, w, 0.00021858087f);
    p = fmaf(p, w, -0.00125372503f);
    p = fmaf(p, w, -0.00417768164f);
    p = fmaf(p, w, 0.246640727f);
    p = fmaf(p, w, 1.50140941f);
  } else {
    w = sqrtf(w) - 3.0f;
    p = -0.000200214257f;
    p = fmaf(p, w, 0.000100950558f);
    p = fmaf(p, w, 0.00134934322f);
    p = fmaf(p, w, -0.00367342844f);
    p = fmaf(p, w, 0.00573950773f);
    p = fmaf(p, w, -0.0076224613f);
    p = fmaf(p, w, 0.00943887047f);
    p = fmaf(p, w, 1.00167406f);
    p = fmaf(p, w, 2.83297682f);
  }
  return p * x;
}

__device__ __forceinline__ float bits_to_normal(unsigned b) {
  float f = __uint_as_float((b >> 9) | 0x3F800000u) - 1.0f;
  const float lo = -0.99999994f;
  float u = fmaxf(lo, f * 2.0f + lo);
  return 1.4142135623730951f * erfinv32(u);
}

// ---------------- fp32 GEMM: C[2048xN=512] = A[2048xK] @ B[512xK]^T + bias ----------------
// MODE 0: row-major fp32 out. MODE 1: scatter fp32 to qT/kT [bh][d][t]. MODE 2: scatter bf16 to xpadT.
template<int MODE>
__global__ __launch_bounds__(256) void gemm_k(const float* __restrict__ A, const float* __restrict__ B,
                                              const float* __restrict__ bias, float* __restrict__ Cout,
                                              int K) {
  __shared__ float As[16][65];
  __shared__ float Bs[16][65];
  int tid = threadIdx.x;
  int tx = tid & 15, ty = tid >> 4;
  int rBase = blockIdx.x * 64;
  int cBase = blockIdx.y * 64;
  float acc[4][4] = {};
  int m = tid & 63, kq = tid >> 6;
  for (int kk = 0; kk < K; kk += 16) {
    float4 av = *(const float4*)(A + (size_t)(rBase + m) * K + kk + kq * 4);
    float4 bv = *(const float4*)(B + (size_t)(cBase + m) * K + kk + kq * 4);
    As[kq*4+0][m] = av.x; As[kq*4+1][m] = av.y; As[kq*4+2][m] = av.z; As[kq*4+3][m] = av.w;
    Bs[kq*4+0][m] = bv.x; Bs[kq*4+1][m] = bv.y; Bs[kq*4+2][m] = bv.z; Bs[kq*4+3][m] = bv.w;
    __syncthreads();
#pragma unroll
    for (int k = 0; k < 16; ++k) {
      float a[4], b[4];
#pragma unroll
      for (int i = 0; i < 4; ++i) a[i] = As[k][ty + 16*i];
#pragma unroll
      for (int j = 0; j < 4; ++j) b[j] = Bs[k][tx + 16*j];
#pragma unroll
      for (int i = 0; i < 4; ++i)
#pragma unroll
        for (int j = 0; j < 4; ++j) acc[i][j] += a[i] * b[j];
    }
    __syncthreads();
  }
#pragma unroll
  for (int i = 0; i < 4; ++i) {
    int r = rBase + ty + 16*i;
    int t = r >> 2, bb = r & 3;
#pragma unroll
    for (int j = 0; j < 4; ++j) {
      int c = cBase + tx + 16*j;
      float v = acc[i][j] + bias[c];
      if (MODE == 0) {
        Cout[(size_t)r * 512 + c] = v;
      } else if (MODE == 1) {
        int h = c >> 6, d = c & 63;
        Cout[((size_t)(bb*8 + h) * 64 + d) * 512 + t] = v;
      } else {
        int h = c >> 6, d = c & 63;
        ((unsigned short*)Cout)[((size_t)((bb*8 + h) * 768) + 256 + t) * 128 + d] = f2bf(v);
      }
    }
  }
}

// fill xpadT channels 64..127: xpadT[bh][256+t][64+dd] = bf16(w[dd][bh])
__global__ void fillw_k(const float* __restrict__ warr, unsigned short* __restrict__ xpad) {
  int e = blockIdx.x * 256 + threadIdx.x;   // < 32*512*64 = 2^20
  int dd = e & 63, t = (e >> 6) & 511, bh = e >> 15;
  xpad[((size_t)(bh * 768) + 256 + t) * 128 + 64 + dd] = f2bf(warr[dd * 32 + bh]);
}

// cos-sim graph: ji_mat (output), top-32 per row, tk_w softmax, S scatter matrix
__global__ __launch_bounds__(256) void graph_k(const float* __restrict__ warr,
                                               float* __restrict__ Sout, float* __restrict__ jiout) {
  __shared__ float wl[64][32];
  __shared__ float cosl[64][65];
  __shared__ float scratch[64][64];
  __shared__ float nrm[64];
  __shared__ float tkv[64][32];
  __shared__ int   tki[64][32];
  int tid = threadIdx.x;
  for (int e = tid; e < 64*32; e += 256) wl[e >> 5][e & 31] = warr[e];
  __syncthreads();
  {
    int i = tid >> 2;
    for (int jj = 0; jj < 16; ++jj) {
      int j = (tid & 3) * 16 + jj;
      float s = 0;
      for (int n = 0; n < 32; ++n) s += wl[i][n] * wl[j][n];
      cosl[i][j] = s;
    }
  }
  __syncthreads();
  if (tid < 64) nrm[tid] = sqrtf(cosl[tid][tid]);
  __syncthreads();
  {
    int i = tid >> 2;
    for (int jj = 0; jj < 16; ++jj) {
      int j = (tid & 3) * 16 + jj;
      float v = cosl[i][j] / (nrm[i] * nrm[j]);
      cosl[i][j] = v;
      scratch[i][j] = v;
    }
  }
  __syncthreads();
  if (tid < 64) {
    int i = tid;
    float mx = -1e30f;
    for (int j = 0; j < 64; ++j) mx = fmaxf(mx, cosl[i][j]);
    float sum = 0;
    for (int j = 0; j < 64; ++j) sum += expf(cosl[i][j] - mx);
    float inv = 1.0f / sum;
    for (int j = 0; j < 64; ++j) jiout[i * 64 + j] = expf(cosl[i][j] - mx) * inv;
    for (int m = 0; m < 32; ++m) {
      float best = -1e30f; int bi = 0;
      for (int j = 0; j < 64; ++j) { float v = scratch[i][j]; if (v > best) { best = v; bi = j; } }
      tkv[i][m] = best; tki[i][m] = bi; scratch[i][bi] = -1e30f;
    }
    float m0 = tkv[i][0], s2 = 0;
    for (int m = 0; m < 32; ++m) s2 += expf(tkv[i][m] - m0);
    float i2 = 1.0f / s2;
    for (int m = 0; m < 32; ++m) tkv[i][m] = expf(tkv[i][m] - m0) * i2;
  }
  __syncthreads();
  for (int e = tid; e < 4096; e += 256) scratch[e >> 6][e & 63] = 0.0f;
  __syncthreads();
  if (tid < 64) for (int m = 0; m < 32; ++m) scratch[tid][tki[tid][m]] = tkv[tid][m];
  __syncthreads();
  for (int e = tid; e < 4096; e += 256) Sout[e] = scratch[e >> 6][e & 63];
}

// qS[bh][j][s] = sum_i S[i][j] * qT[bh][i][s]
__global__ __launch_bounds__(256) void qs_k(const float* __restrict__ qT, const float* __restrict__ S,
                                            float* __restrict__ qS) {
  __shared__ float Sl[64][64];
  int tid = threadIdx.x;
  for (int e = tid; e < 4096; e += 256) Sl[e >> 6][e & 63] = S[e];
  __syncthreads();
  int bh = blockIdx.x;
  int s = blockIdx.y * 64 + (tid & 63);
  int jg = (tid >> 6) * 16;
  float acc[16] = {};
  const float* qb = qT + (size_t)bh * 64 * 512 + s;
  for (int i = 0; i < 64; ++i) {
    float qv = qb[i * 512];
#pragma unroll
    for (int jj = 0; jj < 16; ++jj) acc[jj] += Sl[i][jg + jj] * qv;
  }
  float* ob = qS + (size_t)bh * 64 * 512 + s;
#pragma unroll
  for (int jj = 0; jj < 16; ++jj) ob[(jg + jj) * 512] = acc[jj];
}

// per (bh,j) circular cross-correlation partials
__global__ __launch_bounds__(256) void ccor_k(const float* __restrict__ qS, const float* __restrict__ kT,
                                              float* __restrict__ part) {
  __shared__ float qr[512], kr[512];
  int tid = threadIdx.x;
  int bj = blockIdx.x;
  const float* q = qS + (size_t)bj * 512;
  const float* k = kT + (size_t)bj * 512;
  qr[tid] = q[tid]; qr[tid + 256] = q[tid + 256];
  kr[tid] = k[tid]; kr[tid + 256] = k[tid + 256];
  __syncthreads();
  int t0 = tid, t1 = tid + 256;
  float a0 = 0, a1 = 0;
  for (int s = 0; s < 512; ++s) {
    float qv = qr[s];
    a0 += qv * kr[(s - t0) & 511];
    a1 += qv * kr[(s - t1) & 511];
  }
  part[(size_t)bj * 512 + t0] = a0;
  part[(size_t)bj * 512 + t1] = a1;
}

__global__ void redmc_k(const float* __restrict__ part, float* __restrict__ mc) {
  int t = blockIdx.x * 256 + threadIdx.x;
  float s = 0;
  for (int p = 0; p < 2048; ++p) s += part[(size_t)p * 512 + t];
  mc[t] = s * (1.0f / 2048.0f);
}

// top-6 + softmax + ks fold + threefry key schedule
__global__ void top6_k(const float* __restrict__ mc, unsigned* metaU, float* tmpc) {
  if (threadIdx.x != 0 || blockIdx.x != 0) return;
  float vals[6]; int idx[6];
  for (int m = 0; m < 6; ++m) {
    float best = -1e30f; int bi = 0;
    for (int t = 0; t < 512; ++t) {
      bool skip = false;
      for (int p = 0; p < m; ++p) if (idx[p] == t) skip = true;
      if (skip) continue;
      float v = mc[t];
      if (v > best) { best = v; bi = t; }
    }
    vals[m] = best; idx[m] = bi;
  }
  float mx = vals[0], s = 0;
  for (int m = 0; m < 6; ++m) s += expf(vals[m] - mx);
  for (int m = 0; m < 6; ++m) tmpc[m] = expf(vals[m] - mx) / s;
  for (int m = 0; m < 6; ++m) {
    metaU[m] = (unsigned)idx[m];
    int ind = idx[m];
    if (ind >= 256) ind = 512 - ind;
    metaU[6 + m] = (unsigned)ind;
    unsigned kk0, kk1; tf_block(0u, 1u, 0u, (unsigned)ind, kk0, kk1);
    unsigned* kp = metaU + 24 + m * 8;
#pragma unroll
    for (int i = 0; i < 4; ++i) {
      unsigned o0, o1;
      tf_block(kk0, kk1, 0u, (unsigned)i, o0, o1);
      kp[2*i]   = o0;
      kp[2*i+1] = o1;
    }
    // key0 -> w1 (normal), key1 -> b1 (uniform), key2 -> w2 (normal), key3 -> b2 (uniform)
  }
}

// conv weights, hi-only bf16, layout [cih][kp][co][slot][j] (half-ci slabs of 16 KB),
// pre-swizzled: ci = cih*64 + ((slot ^ (co&7))<<3) + j  -> conflict-free LDS reads.
// jax source linear index e over (co,ci,kp). grid 2048 x 8/thread.
__global__ __launch_bounds__(256) void genw_k(float* __restrict__ ws, const unsigned* __restrict__ metaU,
                                              int sel, int which) {
  int ks = (int)metaU[6 + sel];
  if (ks <= 1) return;
  int n = ks << 14;
  int half = ks << 13;
  const unsigned* kp_ = metaU + 24 + sel * 8 + (which ? 4 : 0);
  unsigned k0 = kp_[0], k1 = kp_[1];
  unsigned short* dst = (unsigned short*)(ws + (which ? OFF_W2 : OFF_W1));
  int base = blockIdx.x * 256 + threadIdx.x;
#pragma unroll
  for (int jj = 0; jj < 8; ++jj) {
    int d = base + jj * 524288;
    if (d < n) {
      int cih = (d >= half) ? 1 : 0;
      int rem = d - (cih ? half : 0);
      int kp = rem >> 13;
      int r2 = rem & 8191;
      int co = r2 >> 6, slot = (r2 >> 3) & 7, j = r2 & 7;
      int ci = cih * 64 + ((slot ^ (co & 7)) << 3) + j;
      unsigned e = (unsigned)((co * 128 + ci) * ks + kp);
      float w = 0.01f * bits_to_normal(tf_bits32(k0, k1, e));
      dst[d] = f2bf(w);
    }
  }
}

__global__ void genb_k(float* __restrict__ ws, const unsigned* __restrict__ metaU, int sel) {
  int ks = (int)metaU[6 + sel];
  if (ks <= 1) return;
  int tid = threadIdx.x;
  int which = tid >> 7;     // 0: b1 (key1), 1: b2 (key3)
  int e = tid & 127;
  const unsigned* kp = metaU + 24 + sel * 8 + (which ? 6 : 2);
  float bound = (float)(1.0 / sqrt((double)(128 * ks)));
  unsigned bits = tf_bits32(kp[0], kp[1], (unsigned)e);
  float f = __uint_as_float((bits >> 9) | 0x3F800000u) - 1.0f;
  float r = f * (2.0f * bound) + (-bound);
  r = fmaxf(-bound, r);
  float* dst = ws + (which ? OFF_B2 : OFF_B1);
  dst[e] = r;
}

// ---------------- MFMA conv: split-K(8) + LDS A-ring + half-ci W slabs ----------------
// Round-10 PMC model: conv was bound by ~7.5 TB/s aggregate L1/L2 delivery; A-operand global
// re-reads were 4.2 GB/conv (256 KB/block/kp). Fix: A lives in a 256-row LDS ring — one new
// 128 B row per kp instead of 256 KB. ci split into two 64-wide passes (acc carried across) so
// ring (256 x 144 B = 36 KB) + W half-slab (16 KB) = 53 KB -> 2 blocks/CU.
// grid (32 bh, 2 tt of 256t, 8 z) = 512 blocks. Wave = 64t x 128co (m=4, n=8; acc 128 VGPR).
// All LDS access patterns at the 8-access/bank structural floor (ring row-pad 144 B; W XOR-swizzle).
// Partials bf16 to SP_OFF buffers; epilogue transposes two 64t-wave-tiles per pass through LDS.
__global__ __launch_bounds__(256, 2) void conv_split(const unsigned short* __restrict__ src,
                                                     const unsigned short* __restrict__ wgl,
                                                     float* __restrict__ wsf,
                                                     const unsigned* __restrict__ metaU,
                                                     int sel, int which) {
  int ks = (int)metaU[6 + sel];
  if (ks <= 1) return;
  __shared__ unsigned short lds[26624];         // ring: 256 rows x 72 shorts (36 KB) | wslab 16 KB
  unsigned short* ring = lds;
  unsigned short* wslab = lds + 18432;
  int bh = blockIdx.x, tt = blockIdx.y, z = blockIdx.z;
  unsigned short* SP = (unsigned short*)(wsf + SP_OFF[which][z]);
  int k0 = (z * ks) / 8, k1 = ((z + 1) * ks) / 8;
  int tid = threadIdx.x;
  int lane = tid & 63, wv = tid >> 6;
  int mrow = lane & 15, quad = lane >> 4;
  int t0 = tt * 256;

  ffrag zero = {0.f, 0.f, 0.f, 0.f};
  ffrag acc[4][8];
#pragma unroll
  for (int m = 0; m < 4; ++m)
#pragma unroll
    for (int n = 0; n < 8; ++n) acc[m][n] = zero;

  if (k0 < k1) {
    for (int cih = 0; cih < 2; ++cih) {
      const unsigned short* wb = wgl + (size_t)cih * ((size_t)ks * 8192);
      const unsigned short* abase = src + ((size_t)(bh * 768 + 257 - ks + t0 + k0)) * 128 + cih * 64;
      __syncthreads();   // previous pass's readers done before refilling ring
      // initial ring fill: rows x = 0..255 of this ci-half (2048 chunks of 16 B)
#pragma unroll
      for (int i = 0; i < 8; ++i) {
        int c = i * 256 + tid; int r = c >> 3, j = c & 7;
        *(float4*)((char*)ring + r * 144 + j * 16) = *(const float4*)(abase + (size_t)r * 128 + j * 8);
      }
      // prefetch W slab k0 + ring row for off=1
      const float4* g4 = (const float4*)wb;
      float4 pf[4];
      {
        const float4* gs = g4 + (size_t)k0 * 1024;
#pragma unroll
        for (int i = 0; i < 4; ++i) pf[i] = gs[i * 256 + tid];
      }
      float4 rowpf = {0,0,0,0};
      if (tid < 8 && k0 + 1 < k1) rowpf = *(const float4*)(abase + (size_t)256 * 128 + tid * 8);

      for (int kp = k0; kp < k1; ++kp) {
        int off = kp - k0;
        __syncthreads();   // readers of previous slab / expired ring row done
#pragma unroll
        for (int i = 0; i < 4; ++i)
          *(float4*)((char*)wslab + (i * 256 + tid) * 16) = pf[i];
        if (off > 0 && tid < 8)
          *(float4*)((char*)ring + ((off + 255) & 255) * 144 + tid * 16) = rowpf;
        if (kp + 1 < k1) {
          const float4* gs = g4 + (size_t)(kp + 1) * 1024;
#pragma unroll
          for (int i = 0; i < 4; ++i) pf[i] = gs[i * 256 + tid];
          if (tid < 8) rowpf = *(const float4*)(abase + (size_t)(off + 256) * 128 + tid * 8);
        }
        __syncthreads();   // slab + new ring row visible
#pragma unroll
        for (int kst = 0; kst < 2; ++kst) {
          bfrag a[4];
#pragma unroll
          for (int m = 0; m < 4; ++m) {
            int tl = wv * 64 + m * 16 + mrow;
            int slot = (off + tl) & 255;
            a[m] = *(const bfrag*)((char*)ring + slot * 144 + kst * 64 + quad * 16);
          }
#pragma unroll
          for (int n = 0; n < 8; ++n) {
            int co = n * 16 + mrow;
            int sl = (kst * 4 + quad) ^ (mrow & 7);
            bfrag b = *(const bfrag*)((char*)wslab + co * 128 + sl * 16);
#pragma unroll
            for (int m = 0; m < 4; ++m)
              acc[m][n] = __builtin_amdgcn_mfma_f32_16x16x32_bf16(a[m], b, acc[m][n], 0, 0, 0);
          }
        }
      }
    }
  }

  // --- coalesced bf16 store epilogue: two 128t passes (2 wave-tiles each) through LDS ---
#pragma unroll
  for (int p = 0; p < 2; ++p) {
    __syncthreads();
    if ((wv >> 1) == p) {
      unsigned short* dst = lds + (wv & 1) * 8192;
#pragma unroll
      for (int m = 0; m < 4; ++m) {
#pragma unroll
        for (int n = 0; n < 8; ++n) {
          int cog = n * 16 + mrow;
#pragma unroll
          for (int r = 0; r < 4; ++r) {
            int tl = m * 16 + quad * 4 + r;
            dst[tl * 128 + cog] = f2bf(acc[m][n][r]);
          }
        }
      }
    }
    __syncthreads();
    // 128t x 128co bf16 = 32 KB contiguous in SP at (bh*512 + t0 + p*128)*128
    float4* spv = (float4*)(SP + ((size_t)(bh * 512) + t0 + p * 128) * 128);
    const float4* lf4 = (const float4*)lds;
#pragma unroll
    for (int k = 0; k < 8; ++k)
      spv[k * 256 + tid] = lf4[k * 256 + tid];
  }
}

// epilogue 1: h = relu(sum_z SPz + b1) -> hpadT bf16   (grid 2048, 4 elems/thread)
__global__ void epi1_k(const float* __restrict__ wsf, const float* __restrict__ bias,
                       unsigned short* __restrict__ hpad,
                       const unsigned* __restrict__ metaU, int sel) {
  int ks = (int)metaU[6 + sel];
  if (ks <= 1) return;
  int base = blockIdx.x * 1024 + threadIdx.x;
#pragma unroll
  for (int j = 0; j < 4; ++j) {
    int e = base + j * 256;   // < 2^21 ; e = (bh*512+t)*128 + c
    int c = e & 127, t = (e >> 7) & 511, bh = e >> 16;
    float v = 0.0f;
#pragma unroll
    for (int z = 0; z < 8; ++z)
      v += bf2f(((const unsigned short*)(wsf + SP_OFF[0][z]))[e]);
    v = fmaxf(v + bias[c], 0.0f);
    hpad[((size_t)(bh * 768) + 256 + t) * 128 + c] = f2bf(v);
  }
}

// epilogue 2: aggA += tc * relu(relu(sum_z SPz + b2) + v2)
__global__ void epi2_k(const float* __restrict__ wsf, const float* __restrict__ bias,
                       const unsigned short* __restrict__ v2pad, float* __restrict__ aggA,
                       const unsigned* __restrict__ metaU, const float* __restrict__ tmpc, int sel) {
  int ks = (int)metaU[6 + sel];
  if (ks <= 1) return;
  float tc = tmpc[sel];
  int base = blockIdx.x * 1024 + threadIdx.x;
#pragma unroll
  for (int j = 0; j < 4; ++j) {
    int e = base + j * 256;
    int c = e & 127, t = (e >> 7) & 511, bh = e >> 16;
    float v = 0.0f;
#pragma unroll
    for (int z = 0; z < 8; ++z)
      v += bf2f(((const unsigned short*)(wsf + SP_OFF[1][z]))[e]);
    v = fmaxf(v + bias[c], 0.0f);
    float v2 = bf2f(v2pad[((size_t)(bh * 768) + 256 + t) * 128 + c]);
    float tb = fmaxf(v + v2, 0.0f);
    aggA[((size_t)(t * 4 + (bh >> 3))) * 1024 + (bh & 7) * 128 + c] += tc * tb;
  }
}

// ks<=1 path: aggA += tc * v2   (grid 2048, 4 elems/thread)
__global__ void resid_k(const unsigned short* __restrict__ xpad, float* __restrict__ aggA,
                        const unsigned* __restrict__ metaU, const float* __restrict__ tmpc, int sel) {
  int ks = (int)metaU[6 + sel];
  if (ks > 1) return;
  float tc = tmpc[sel];
  int base = blockIdx.x * 1024 + threadIdx.x;
#pragma unroll
  for (int j = 0; j < 4; ++j) {
    int e = base + j * 256;   // < 32*512*128 = 2^21
    int c = e & 127, t = (e >> 7) & 511, bh = e >> 16;
    float v2 = bf2f(xpad[((size_t)(bh * 768) + 256 + t) * 128 + c]);
    aggA[((size_t)(t * 4 + (bh >> 3))) * 1024 + (bh & 7) * 128 + c] += tc * v2;
  }
}

// dim_cor partial: for (bh,sel): P[i][j] = sum_s qT[i][s]*kT[j][(s-t*)&511]; atomic += tc/32 * P
__global__ __launch_bounds__(256) void dimcor_k(const float* __restrict__ qT, const float* __restrict__ kT,
                                                float* __restrict__ dima, const unsigned* __restrict__ metaU,
                                                const float* __restrict__ tmpc) {
  __shared__ float qs[64][33];
  __shared__ float ksh[64][33];
  int bh = blockIdx.x, sel = blockIdx.y;
  int tstar = (int)metaU[sel];
  float scale = tmpc[sel] * (1.0f / 32.0f);
  int tid = threadIdx.x;
  int tx = tid & 15, ty = tid >> 4;
  float acc[4][4] = {};
  const float* qb = qT + (size_t)bh * 64 * 512;
  const float* kb = kT + (size_t)bh * 64 * 512;
  int ss = tid & 31, rr = tid >> 5;
  for (int s0 = 0; s0 < 512; s0 += 32) {
#pragma unroll
    for (int l = 0; l < 8; ++l) {
      int row = rr + 8 * l;
      qs[row][ss]  = qb[row * 512 + s0 + ss];
      ksh[row][ss] = kb[row * 512 + ((s0 + ss - tstar) & 511)];
    }
    __syncthreads();
#pragma unroll
    for (int s = 0; s < 32; ++s) {
      float a[4], b[4];
#pragma unroll
      for (int i = 0; i < 4; ++i) a[i] = qs[ty + 16*i][s];
#pragma unroll
      for (int j = 0; j < 4; ++j) b[j] = ksh[tx + 16*j][s];
#pragma unroll
      for (int i = 0; i < 4; ++i)
#pragma unroll
        for (int j = 0; j < 4; ++j) acc[i][j] += a[i] * b[j];
    }
    __syncthreads();
  }
#pragma unroll
  for (int i = 0; i < 4; ++i)
#pragma unroll
    for (int j = 0; j < 4; ++j)
      atomicAdd(&dima[(ty + 16*i) * 64 + tx + 16*j], acc[i][j] * scale);
}

__global__ void dsm_k(const float* __restrict__ dima, float* __restrict__ out) {
  int i = threadIdx.x;
  if (i >= 64) return;
  float mx = -1e30f;
  for (int j = 0; j < 64; ++j) mx = fmaxf(mx, 0.125f * dima[i * 64 + j]);
  float s = 0;
  for (int j = 0; j < 64; ++j) s += expf(0.125f * dima[i * 64 + j] - mx);
  float inv = 1.0f / s;
  for (int j = 0; j < 64; ++j) out[i * 64 + j] = expf(0.125f * dima[i * 64 + j] - mx) * inv;
}

extern "C" void kernel_launch(void* const* d_in, const int* in_sizes, int n_in,
                              void* d_out, int out_size, void* d_ws, size_t ws_size,
                              hipStream_t stream) {
  (void)in_sizes; (void)n_in; (void)out_size; (void)ws_size;
  const float* query  = (const float*)d_in[0];
  const float* key_in = (const float*)d_in[1];
  const float* value  = (const float*)d_in[2];
  const float* Wq = (const float*)d_in[4];
  const float* bq = (const float*)d_in[5];
  const float* Wk = (const float*)d_in[6];
  const float* bk = (const float*)d_in[7];
  const float* Wv = (const float*)d_in[8];
  const float* bv = (const float*)d_in[9];
  const float* Wo = (const float*)d_in[10];
  const float* bo = (const float*)d_in[11];
  const float* warr = (const float*)d_in[12];
  float* out = (float*)d_out;
  float* ws = (float*)d_ws;
  unsigned* metaU = (unsigned*)(ws + OFF_META);
  float* tmpc = ws + OFF_TMPC;
  unsigned short* xpad = (unsigned short*)(ws + OFF_XT);
  unsigned short* hpad = (unsigned short*)(ws + OFF_H);
  float* aggA = ws + OFF_AGGA;

  // zero: aggA (accumulated), xpad/hpad pad rows, dim_cor accum
  hipMemsetAsync(aggA, 0, (size_t)2048 * 1024 * 4, stream);
  hipMemsetAsync(xpad, 0, (size_t)32 * 768 * 128 * 2, stream);
  hipMemsetAsync(hpad, 0, (size_t)32 * 768 * 128 * 2, stream);
  hipMemsetAsync(ws + OFF_DIMA, 0, 4096 * sizeof(float), stream);

  // projections
  gemm_k<1><<<dim3(32, 8), 256, 0, stream>>>(query,  Wq, bq, ws + OFF_QT, 512);
  gemm_k<1><<<dim3(32, 8), 256, 0, stream>>>(key_in, Wk, bk, ws + OFF_KT, 512);
  gemm_k<2><<<dim3(32, 8), 256, 0, stream>>>(value,  Wv, bv, (float*)xpad, 512);
  fillw_k<<<4096, 256, 0, stream>>>(warr, xpad);

  // cos graph / ji_mat / S
  graph_k<<<1, 256, 0, stream>>>(warr, ws + OFF_S, out + 1048576 + 4096);

  // mean_corr via folded sparse-weighted circular correlation
  qs_k<<<dim3(32, 8), 256, 0, stream>>>(ws + OFF_QT, ws + OFF_S, ws + OFF_QS);
  ccor_k<<<2048, 256, 0, stream>>>(ws + OFF_QS, ws + OFF_KT, ws + OFF_PART);
  redmc_k<<<2, 256, 0, stream>>>(ws + OFF_PART, ws + OFF_MC);
  top6_k<<<1, 64, 0, stream>>>(ws + OFF_MC, metaU, tmpc);

  // temporal blocks (fixed worst-case grids; device-side ks gates the work).
  // Per sel: genW1 -> conv1 (partials may clobber W2 slot) -> epi1 -> genW2 -> conv2
  // (partials clobber dead W1 slot) -> epi2 -> resid.
  for (int sel = 0; sel < 6; ++sel) {
    genw_k<<<2048, 256, 0, stream>>>(ws, metaU, sel, 0);
    genb_k<<<1, 256, 0, stream>>>(ws, metaU, sel);
    conv_split<<<dim3(32, 2, 8), 256, 0, stream>>>(
        xpad, (unsigned short*)(ws + OFF_W1), ws, metaU, sel, 0);
    epi1_k<<<2048, 256, 0, stream>>>(ws, ws + OFF_B1, hpad, metaU, sel);
    genw_k<<<2048, 256, 0, stream>>>(ws, metaU, sel, 1);
    conv_split<<<dim3(32, 2, 8), 256, 0, stream>>>(
        hpad, (unsigned short*)(ws + OFF_W2), ws, metaU, sel, 1);
    epi2_k<<<2048, 256, 0, stream>>>(ws, ws + OFF_B2, xpad, aggA, metaU, tmpc, sel);
    resid_k<<<2048, 256, 0, stream>>>(xpad, aggA, metaU, tmpc, sel);
  }

  // output projection (aggA is already [ (t*4+b) ][ h*128+c ])
  gemm_k<0><<<dim3(32, 8), 256, 0, stream>>>(aggA, Wo, bo, out, 1024);

  // dim_cor
  dimcor_k<<<dim3(32, 6), 256, 0, stream>>>(ws + OFF_QT, ws + OFF_KT, ws + OFF_DIMA, metaU, tmpc);
  dsm_k<<<1, 64, 0, stream>>>(ws + OFF_DIMA, out + 1048576);
}